// Round 13
// baseline (318.724 us; speedup 1.0000x reference)
//
#include <hip/hip_runtime.h>
#include <hip/hip_bf16.h>
#include <cstdint>
#include <cstddef>

// B=2, T=2048, D=1024, H=16, DH=64, CTX=2048.  M = B*T = 4096.

using bf16x8 = __attribute__((ext_vector_type(8))) __bf16;
using f32x4  = __attribute__((ext_vector_type(4))) float;

#define VMCNT(n) asm volatile("s_waitcnt vmcnt(" #n ")" ::: "memory")
#define LGKM0()  do { asm volatile("s_waitcnt lgkmcnt(0)" ::: "memory"); \
                      __builtin_amdgcn_sched_barrier(0); } while (0)
#define BARF()   do { asm volatile("" ::: "memory"); __builtin_amdgcn_s_barrier(); \
                      asm volatile("" ::: "memory"); } while (0)

__device__ __forceinline__ short f2b(float f) {
  uint32_t u = __builtin_bit_cast(uint32_t, f);
  uint32_t r = (u + 0x7FFFu + ((u >> 16) & 1u)) >> 16;
  return (short)r;
}
__device__ __forceinline__ float b2f(short s) {
  uint32_t u = ((uint32_t)(uint16_t)s) << 16;
  return __builtin_bit_cast(float, u);
}
// truncation pack of two f32 -> two bf16 in a u32 (P values in [0,1]; bias <0.4%)
__device__ __forceinline__ uint32_t pack2(float a, float b) {
  return (__builtin_bit_cast(uint32_t, a) >> 16) |
         (__builtin_bit_cast(uint32_t, b) & 0xFFFF0000u);
}

__device__ __forceinline__ void gload16(const short* g, short* l) {
  __builtin_amdgcn_global_load_lds(
      (const __attribute__((address_space(1))) void*)g,
      (__attribute__((address_space(3))) void*)l, 16, 0, 0);
}

// ---------------------------------------------------------------------------
// Staging, 64-col (128B) rows, XOR (row&7) swizzle applied on GLOBAL source,
// linear LDS dest (global_load_lds requirement).  Zero-bank-conflict verified.
// ---------------------------------------------------------------------------
template<int ROWS>  // 256 threads, ROWS/32 loads per thread
__device__ __forceinline__ void stage_swz(const short* __restrict__ g, int ldg,
                                          short* lds, int tid) {
#pragma unroll
  for (int jj = 0; jj < ROWS / 32; ++jj) {
    int row = jj * 32 + (tid >> 3);
    int seg = tid & 7;
    gload16(g + (size_t)row * ldg + ((seg ^ (row & 7)) << 3),
            lds + row * 64 + (seg << 3));
  }
}

// 512 threads, one 64-row round per call (1 gload16/thread)
__device__ __forceinline__ void stage_round512(const short* __restrict__ g, int ldg,
                                               short* lds, int tid, int rbase) {
  int row = rbase + (tid >> 3);
  int seg = tid & 7;
  gload16(g + (size_t)row * ldg + ((seg ^ (row & 7)) << 3),
          lds + row * 64 + (seg << 3));
}

__device__ __forceinline__ bf16x8 frag64(const short* lds, int row, int seg) {
  return *(const bf16x8*)(lds + row * 64 + ((seg ^ (row & 7)) << 3));
}

__device__ __forceinline__ f32x4 mma16(bf16x8 a, bf16x8 b, f32x4 c) {
  return __builtin_amdgcn_mfma_f32_16x16x32_bf16(a, b, c, 0, 0, 0);
}

// ---------------------------------------------------------------------------
// Fused weight conversion f32 -> bf16
// ---------------------------------------------------------------------------
__global__ void k_cvt_all(const float* __restrict__ wqkv, short* __restrict__ oqkv,
                          const float* __restrict__ wproj, short* __restrict__ oproj,
                          const float* __restrict__ wgate, short* __restrict__ ogate,
                          const float* __restrict__ wup, short* __restrict__ oup,
                          const float* __restrict__ wdown, short* __restrict__ odown) {
  int bid = blockIdx.x;
  const float* src;
  short* dst;
  int off;
  if (bid < 3072)       { src = wqkv;  dst = oqkv;  off = bid; }
  else if (bid < 4096)  { src = wproj; dst = oproj; off = bid - 3072; }
  else if (bid < 8192)  { src = wgate; dst = ogate; off = bid - 4096; }
  else if (bid < 12288) { src = wup;   dst = oup;   off = bid - 8192; }
  else                  { src = wdown; dst = odown; off = bid - 12288; }
  int i = off * 256 + threadIdx.x;
  float4 v = ((const float4*)src)[i];
  ((short4*)dst)[i] = make_short4(f2b(v.x), f2b(v.y), f2b(v.z), f2b(v.w));
}

// ---------------------------------------------------------------------------
// RMSNorm: one block (256 thr) per row of 1024 f32 -> bf16
// ---------------------------------------------------------------------------
__global__ void k_rms(const float* __restrict__ x, const float* __restrict__ w,
                      short* __restrict__ out) {
  int row = blockIdx.x;
  int tid = threadIdx.x;
  float4 v = *(const float4*)(x + (size_t)row * 1024 + tid * 4);
  float ss = v.x * v.x + v.y * v.y + v.z * v.z + v.w * v.w;
#pragma unroll
  for (int o = 1; o < 64; o <<= 1) ss += __shfl_xor(ss, o);
  __shared__ float sred[4];
  int wid = tid >> 6, lane = tid & 63;
  if (lane == 0) sred[wid] = ss;
  __syncthreads();
  float tot = sred[0] + sred[1] + sred[2] + sred[3];
  float r = rsqrtf(tot * (1.0f / 1024.0f) + 1e-6f);
  float4 wv = *(const float4*)(w + tid * 4);
  short4 o = make_short4(f2b(v.x * r * wv.x), f2b(v.y * r * wv.y),
                         f2b(v.z * r * wv.z), f2b(v.w * r * wv.w));
  *(short4*)(out + (size_t)row * 1024 + tid * 4) = o;
}

// ---------------------------------------------------------------------------
// QKV triple-B kernel: q,k,v = A @ {Wq,Wk,Wv}^T share the A tile.
// BM=128, BN=128 per operand, BK=64, 8 waves.  Grid 256 = 1 block/CU.
// ---------------------------------------------------------------------------
__global__ __launch_bounds__(512) void k_qkv(
    const short* __restrict__ A, const short* __restrict__ W,
    short* __restrict__ q_b, short* __restrict__ k_b, short* __restrict__ vT_b,
    float* __restrict__ kc, float* __restrict__ vc) {
  const int K = 1024, nk = 16;
  __shared__ short As[2][128 * 64];  // 32 KB
  __shared__ short Bq[2][128 * 64];  // 32 KB
  __shared__ short Bk[2][128 * 64];  // 32 KB
  __shared__ short Bv[2][128 * 64];  // 32 KB
  int tid = threadIdx.x;
  int bid = blockIdx.x;
  int swz = (bid & 7) * 32 + (bid >> 3);  // nwg = 256
  int bx = swz & 7, by = swz >> 3;
  int m0 = by * 128, n0 = bx * 128;
  int w = tid >> 6, l = tid & 63;
  int wr = w >> 2, wc = w & 3;
  int lr = l & 15, lseg = l >> 4;
  f32x4 aq[4][2] = {}, ak[4][2] = {}, av[4][2] = {};
  const short* Ab = A + (size_t)m0 * K;
  const short* Qb = W + (size_t)n0 * K;
  const short* Kb = W + (size_t)(1024 + n0) * K;
  const short* Vb = W + (size_t)(2048 + n0) * K;

  // prologue: tile0 all operands (8 loads) + A(1) (2 loads, newest)
  stage_round512(Ab, K, &As[0][0], tid, 0);
  stage_round512(Ab, K, &As[0][0], tid, 64);
  stage_round512(Qb, K, &Bq[0][0], tid, 0);
  stage_round512(Qb, K, &Bq[0][0], tid, 64);
  stage_round512(Kb, K, &Bk[0][0], tid, 0);
  stage_round512(Kb, K, &Bk[0][0], tid, 64);
  stage_round512(Vb, K, &Bv[0][0], tid, 0);
  stage_round512(Vb, K, &Bv[0][0], tid, 64);
  stage_round512(Ab + 64, K, &As[1][0], tid, 0);
  stage_round512(Ab + 64, K, &As[1][0], tid, 64);

  bf16x8 a[4][2], b[2][2];
#pragma unroll 2
  for (int t = 0; t < nk; ++t) {
    short* Sa = &As[t & 1][0];
    short* Sq = &Bq[t & 1][0];
    short* Sk = &Bk[t & 1][0];
    short* Sv = &Bv[t & 1][0];
    short* SqN = &Bq[(t + 1) & 1][0];
    short* SkN = &Bk[(t + 1) & 1][0];
    short* SvN = &Bv[(t + 1) & 1][0];
    const short* Ag2 = Ab + (size_t)(t + 2) * 64;
    const short* Qg1 = Qb + (size_t)(t + 1) * 64;
    const short* Kg1 = Kb + (size_t)(t + 1) * 64;
    const short* Vg1 = Vb + (size_t)(t + 1) * 64;
    bool pf1 = (t + 1 < nk), pf2 = (t + 2 < nk);

    // boundary: tile t resident; keep A(t+2)'s 2 loads in flight
    VMCNT(2);
    BARF();

    // -- P1: q.  reads a(8) + bq(4); stage Bq(t+1), Bk(t+1)
#pragma unroll
    for (int i = 0; i < 4; ++i)
#pragma unroll
      for (int kk = 0; kk < 2; ++kk)
        a[i][kk] = frag64(Sa, wr * 64 + i * 16 + lr, kk * 4 + lseg);
#pragma unroll
    for (int j = 0; j < 2; ++j)
#pragma unroll
      for (int kk = 0; kk < 2; ++kk)
        b[j][kk] = frag64(Sq, wc * 32 + j * 16 + lr, kk * 4 + lseg);
    if (pf1) {
      stage_round512(Qg1, K, SqN, tid, 0);
      stage_round512(Qg1, K, SqN, tid, 64);
      stage_round512(Kg1, K, SkN, tid, 0);
      stage_round512(Kg1, K, SkN, tid, 64);
    }
    BARF();
    LGKM0();
    __builtin_amdgcn_s_setprio(1);
#pragma unroll
    for (int i = 0; i < 4; ++i)
#pragma unroll
      for (int j = 0; j < 2; ++j) {
        aq[i][j] = mma16(a[i][0], b[j][0], aq[i][j]);
        aq[i][j] = mma16(a[i][1], b[j][1], aq[i][j]);
      }
    __builtin_amdgcn_s_setprio(0);

    // -- P2: k.  reads bk(4); stage Bv(t+1)
#pragma unroll
    for (int j = 0; j < 2; ++j)
#pragma unroll
      for (int kk = 0; kk < 2; ++kk)
        b[j][kk] = frag64(Sk, wc * 32 + j * 16 + lr, kk * 4 + lseg);
    if (pf1) {
      stage_round512(Vg1, K, SvN, tid, 0);
      stage_round512(Vg1, K, SvN, tid, 64);
    }
    BARF();
    LGKM0();
    __builtin_amdgcn_s_setprio(1);
#pragma unroll
    for (int i = 0; i < 4; ++i)
#pragma unroll
      for (int j = 0; j < 2; ++j) {
        ak[i][j] = mma16(a[i][0], b[j][0], ak[i][j]);
        ak[i][j] = mma16(a[i][1], b[j][1], ak[i][j]);
      }
    __builtin_amdgcn_s_setprio(0);

    // -- P3: v.  reads bv(4); stage A(t+2) -> Sa (a-reads done since BARF2)
#pragma unroll
    for (int j = 0; j < 2; ++j)
#pragma unroll
      for (int kk = 0; kk < 2; ++kk)
        b[j][kk] = frag64(Sv, wc * 32 + j * 16 + lr, kk * 4 + lseg);
    if (pf2) {
      stage_round512(Ag2, K, Sa, tid, 0);
      stage_round512(Ag2, K, Sa, tid, 64);
    }
    BARF();
    LGKM0();
    __builtin_amdgcn_s_setprio(1);
#pragma unroll
    for (int i = 0; i < 4; ++i)
#pragma unroll
      for (int j = 0; j < 2; ++j) {
        av[i][j] = mma16(a[i][0], b[j][0], av[i][j]);
        av[i][j] = mma16(a[i][1], b[j][1], av[i][j]);
      }
    __builtin_amdgcn_s_setprio(0);
  }

  // epilogue: frag col = lr (n), row = lseg*4 + r (m)
#pragma unroll
  for (int i = 0; i < 4; ++i) {
#pragma unroll
    for (int j = 0; j < 2; ++j) {
#pragma unroll
      for (int r = 0; r < 4; ++r) {
        int m = m0 + wr * 64 + i * 16 + lseg * 4 + r;
        int n = n0 + wc * 32 + j * 16 + lr;
        int hh = n >> 6, dh = n & 63;
        int b_ = m >> 11, tt = m & 2047;
        int bh = b_ * 16 + hh;
        size_t idx = ((size_t)bh * 2048 + tt) * 64 + dh;
        q_b[idx] = f2b(aq[i][j][r]);
        float fk = ak[i][j][r];
        k_b[idx] = f2b(fk);
        kc[idx] = fk;
        float fv = av[i][j][r];
        vT_b[((size_t)bh * 64 + dh) * 2048 + tt] = f2b(fv);
        vc[idx] = fv;
      }
    }
  }
}

// ---------------------------------------------------------------------------
// Fused MLP gate+up with N-walk: act = silu(A@Wg^T) * (A@Wu^T).
// Grid 256 (16M x 16 N-pairs); each block does 2 adjacent N-tiles of 128
// sequentially (2nd half's A re-reads hit this XCD's L2).
// Per half: tile 256x128, BK=64, 8 waves, 4 phases/K-tile, vmcnt(4).
// ---------------------------------------------------------------------------
__global__ __launch_bounds__(512) void k_mlp(
    const short* __restrict__ A, const short* __restrict__ Wg,
    const short* __restrict__ Wu, short* __restrict__ outb) {
  const int K = 1024, N = 4096, nk = 16;
  __shared__ short As[2][256 * 64];  // 64 KB
  __shared__ short Bg[2][128 * 64];  // 32 KB
  __shared__ short Bu[2][128 * 64];  // 32 KB
  int tid = threadIdx.x;
  int bid = blockIdx.x;
  int swz = (bid & 7) * 32 + (bid >> 3);  // nwg = 256
  int bxp = swz & 15, by = swz >> 4;
  int m0 = by * 256;
  int w = tid >> 6, l = tid & 63;
  int wr = w >> 2, wc = w & 3;
  int lr = l & 15, lseg = l >> 4;
  const short* Ab = A + (size_t)m0 * K;

#pragma unroll 1
  for (int hf = 0; hf < 2; ++hf) {
    int n0 = (bxp * 2 + hf) * 128;
    const short* Gb = Wg + (size_t)n0 * K;
    const short* Ub = Wu + (size_t)n0 * K;
    f32x4 aG[2][4][2] = {}, aU[2][4][2] = {};  // [qm][i][j]

    // prologue: A(0)x4, Bg(0)x2, Bu(0)x2, A(1)x4  (A(1) newest for vmcnt(4))
    stage_round512(Ab, K, &As[0][0], tid, 0);
    stage_round512(Ab, K, &As[0][0], tid, 64);
    stage_round512(Ab, K, &As[0][0], tid, 128);
    stage_round512(Ab, K, &As[0][0], tid, 192);
    stage_round512(Gb, K, &Bg[0][0], tid, 0);
    stage_round512(Gb, K, &Bg[0][0], tid, 64);
    stage_round512(Ub, K, &Bu[0][0], tid, 0);
    stage_round512(Ub, K, &Bu[0][0], tid, 64);
    stage_round512(Ab + 64, K, &As[1][0], tid, 0);
    stage_round512(Ab + 64, K, &As[1][0], tid, 64);
    stage_round512(Ab + 64, K, &As[1][0], tid, 128);
    stage_round512(Ab + 64, K, &As[1][0], tid, 192);

    bf16x8 a0[4][2], a1[4][2], bg[2][2], bu[2][2];
#pragma unroll 2
    for (int t = 0; t < nk; ++t) {
      short* Sa  = &As[t & 1][0];
      short* Sg  = &Bg[t & 1][0];
      short* Su  = &Bu[t & 1][0];
      short* SgN = &Bg[(t + 1) & 1][0];
      short* SuN = &Bu[(t + 1) & 1][0];
      const short* Ag2 = Ab + (size_t)(t + 2) * 64;
      const short* Gg1 = Gb + (size_t)(t + 1) * 64;
      const short* Ug1 = Ub + (size_t)(t + 1) * 64;
      bool pf1 = (t + 1 < nk), pf2 = (t + 2 < nk);

      // boundary: tile t resident; keep A(t+1)x4 in flight
      VMCNT(4);
      BARF();

      // -- P1: gate.qm0
#pragma unroll
      for (int i = 0; i < 4; ++i)
#pragma unroll
        for (int kk = 0; kk < 2; ++kk)
          a0[i][kk] = frag64(Sa, wr * 128 + i * 16 + lr, kk * 4 + lseg);
#pragma unroll
      for (int j = 0; j < 2; ++j)
#pragma unroll
        for (int kk = 0; kk < 2; ++kk)
          bg[j][kk] = frag64(Sg, wc * 32 + j * 16 + lr, kk * 4 + lseg);
      if (pf1) {
        stage_round512(Gg1, K, SgN, tid, 0);
        stage_round512(Gg1, K, SgN, tid, 64);
        stage_round512(Ug1, K, SuN, tid, 0);
        stage_round512(Ug1, K, SuN, tid, 64);
      }
      BARF();
      LGKM0();
      __builtin_amdgcn_s_setprio(1);
#pragma unroll
      for (int i = 0; i < 4; ++i)
#pragma unroll
        for (int j = 0; j < 2; ++j) {
          aG[0][i][j] = mma16(a0[i][0], bg[j][0], aG[0][i][j]);
          aG[0][i][j] = mma16(a0[i][1], bg[j][1], aG[0][i][j]);
        }
      __builtin_amdgcn_s_setprio(0);

      // -- P2: up.qm0 (reuse a0)
#pragma unroll
      for (int j = 0; j < 2; ++j)
#pragma unroll
        for (int kk = 0; kk < 2; ++kk)
          bu[j][kk] = frag64(Su, wc * 32 + j * 16 + lr, kk * 4 + lseg);
      if (pf2) {
        stage_round512(Ag2, K, Sa, tid, 0);
        stage_round512(Ag2, K, Sa, tid, 128);
      }
      BARF();
      LGKM0();
      __builtin_amdgcn_s_setprio(1);
#pragma unroll
      for (int i = 0; i < 4; ++i)
#pragma unroll
        for (int j = 0; j < 2; ++j) {
          aU[0][i][j] = mma16(a0[i][0], bu[j][0], aU[0][i][j]);
          aU[0][i][j] = mma16(a0[i][1], bu[j][1], aU[0][i][j]);
        }
      __builtin_amdgcn_s_setprio(0);

      // -- P3: gate.qm1 (reuse bg)
#pragma unroll
      for (int i = 0; i < 4; ++i)
#pragma unroll
        for (int kk = 0; kk < 2; ++kk)
          a1[i][kk] = frag64(Sa, wr * 128 + 64 + i * 16 + lr, kk * 4 + lseg);
      BARF();
      LGKM0();
      __builtin_amdgcn_s_setprio(1);
#pragma unroll
      for (int i = 0; i < 4; ++i)
#pragma unroll
        for (int j = 0; j < 2; ++j) {
          aG[1][i][j] = mma16(a1[i][0], bg[j][0], aG[1][i][j]);
          aG[1][i][j] = mma16(a1[i][1], bg[j][1], aG[1][i][j]);
        }
      __builtin_amdgcn_s_setprio(0);

      // -- P4: up.qm1 (reuse a1, bu); stage A(t+2) r1,r3 (rows read at P3)
      if (pf2) {
        stage_round512(Ag2, K, Sa, tid, 64);
        stage_round512(Ag2, K, Sa, tid, 192);
      }
      BARF();
      __builtin_amdgcn_s_setprio(1);
#pragma unroll
      for (int i = 0; i < 4; ++i)
#pragma unroll
        for (int j = 0; j < 2; ++j) {
          aU[1][i][j] = mma16(a1[i][0], bu[j][0], aU[1][i][j]);
          aU[1][i][j] = mma16(a1[i][1], bu[j][1], aU[1][i][j]);
        }
      __builtin_amdgcn_s_setprio(0);
    }

    // epilogue: act = silu(g) * u, bf16
#pragma unroll
    for (int qm = 0; qm < 2; ++qm) {
#pragma unroll
      for (int i = 0; i < 4; ++i) {
#pragma unroll
        for (int j = 0; j < 2; ++j) {
#pragma unroll
          for (int r = 0; r < 4; ++r) {
            int m = m0 + wr * 128 + qm * 64 + i * 16 + lseg * 4 + r;
            int n = n0 + wc * 32 + j * 16 + lr;
            float g = aG[qm][i][j][r];
            float u = aU[qm][i][j][r];
            float s = g / (1.0f + __expf(-g));
            outb[(size_t)m * N + n] = f2b(s * u);
          }
        }
      }
    }
    BARF();  // all waves done with LDS before next half re-stages
  }
}

// ---------------------------------------------------------------------------
// Skinny GEMM v2: 256x64 tile, BK=64, 4 waves (2M x 2N, wave 128x32):
// 32 MFMA per 20 ds_reads per K-tile (was 16/12), ONE barrier per K-tile.
// LDS 80 KB exactly -> 2 blocks/CU.  Stage of tile u+1 issued right after
// the boundary barrier into the opposite slot (WAR-clean: all waves' reads
// of that slot completed before their previous lgkm0->MFMA->barrier).
// outf[m,n] = C + res[m,n]   (proj, down; grid 16Mx16N = 256)
// ---------------------------------------------------------------------------
__global__ __launch_bounds__(256, 2) void k_gemm_skinny(
    const short* __restrict__ A, const short* __restrict__ Bw,
    int M, int N, int K, int gx,
    const float* __restrict__ res, float* __restrict__ outf) {
  __shared__ short As[2][256 * 64];  // 64 KB
  __shared__ short Bs[2][64 * 64];   // 16 KB  (80 KB total)
  int tid = threadIdx.x;
  int nwg = gridDim.x, bid = blockIdx.x;
  int swz = (bid & 7) * (nwg >> 3) + (bid >> 3);
  int bx = swz % gx, by = swz / gx;
  int m0 = by * 256, n0 = bx * 64;
  int w = tid >> 6, l = tid & 63;
  int wr = w >> 1, wc = w & 1;   // wave tile 128(M) x 32(N)
  int lr = l & 15, lseg = l >> 4;
  f32x4 acc[8][2] = {};
  int nk = K >> 6;
  const short* Ab = A + (size_t)m0 * K;
  const short* Bb = Bw + (size_t)n0 * K;

  // prologue: tile 0 (10 loads/thread)
  stage_swz<256>(Ab, K, &As[0][0], tid);
  stage_swz<64>(Bb, K, &Bs[0][0], tid);

  bf16x8 a[4][2], b[2][2];
#pragma unroll 1
  for (int u = 0; u < nk; ++u) {
    int s = u & 1;
    VMCNT(0);   // tile u resident
    BARF();     // all waves' reads of slot s^1 are complete
    if (u + 1 < nk) {
      stage_swz<256>(Ab + (u + 1) * 64, K, &As[s ^ 1][0], tid);
      stage_swz<64>(Bb + (u + 1) * 64, K, &Bs[s ^ 1][0], tid);
    }
    const short* Asl = &As[s][0];
    const short* Bsl = &Bs[s][0];
    // P1: rows 0..63 of wave's 128 (i = 0..3)
#pragma unroll
    for (int i = 0; i < 4; ++i)
#pragma unroll
      for (int kk = 0; kk < 2; ++kk)
        a[i][kk] = frag64(Asl, wr * 128 + i * 16 + lr, kk * 4 + lseg);
#pragma unroll
    for (int j = 0; j < 2; ++j)
#pragma unroll
      for (int kk = 0; kk < 2; ++kk)
        b[j][kk] = frag64(Bsl, wc * 32 + j * 16 + lr, kk * 4 + lseg);
    LGKM0();
    __builtin_amdgcn_s_setprio(1);
#pragma unroll
    for (int i = 0; i < 4; ++i)
#pragma unroll
      for (int j = 0; j < 2; ++j) {
        acc[i][j] = mma16(a[i][0], b[j][0], acc[i][j]);
        acc[i][j] = mma16(a[i][1], b[j][1], acc[i][j]);
      }
    __builtin_amdgcn_s_setprio(0);
    // P2: rows 64..127 (i = 4..7)
#pragma unroll
    for (int i = 0; i < 4; ++i)
#pragma unroll
      for (int kk = 0; kk < 2; ++kk)
        a[i][kk] = frag64(Asl, wr * 128 + 64 + i * 16 + lr, kk * 4 + lseg);
    LGKM0();
    __builtin_amdgcn_s_setprio(1);
#pragma unroll
    for (int i = 0; i < 4; ++i)
#pragma unroll
      for (int j = 0; j < 2; ++j) {
        acc[4 + i][j] = mma16(a[i][0], b[j][0], acc[4 + i][j]);
        acc[4 + i][j] = mma16(a[i][1], b[j][1], acc[4 + i][j]);
      }
    __builtin_amdgcn_s_setprio(0);
  }

#pragma unroll
  for (int i = 0; i < 8; ++i) {
#pragma unroll
    for (int j = 0; j < 2; ++j) {
#pragma unroll
      for (int r = 0; r < 4; ++r) {
        int m = m0 + wr * 128 + i * 16 + lseg * 4 + r;
        int n = n0 + wc * 32 + j * 16 + lr;
        outf[(size_t)m * N + n] = acc[i][j][r] + res[(size_t)m * N + n];
      }
    }
  }
}

// ---------------------------------------------------------------------------
// Causal flash attention v4 — balanced pairing + ring-3 counted-vmcnt
// prefetch + interleaved c-groups via phase-split loops.
// ---------------------------------------------------------------------------
template<int NC>
__device__ __forceinline__ void attn_tile(
    const short* __restrict__ Ksl, const short* __restrict__ Vsl,
    short* __restrict__ pw,
    const bf16x8 (&qf)[2][2], f32x4 (&acc)[2][4],
    float (&mrow)[2], float (&dden)[2],
    int kv0, int qb0, int qb1, bool band0, bool band1,
    int lr, int g) {
  // hoisted K and V fragments (shared across c-groups)
  bf16x8 kf[4][2], vb[2][4];
#pragma unroll
  for (int i = 0; i < 4; ++i)
#pragma unroll
    for (int kk = 0; kk < 2; ++kk)
      kf[i][kk] = frag64(Ksl, i * 16 + lr, kk * 4 + g);
#pragma unroll
  for (int kk = 0; kk < 2; ++kk)
#pragma unroll
    for (int jf = 0; jf < 4; ++jf)
      vb[kk][jf] = frag64(Vsl, jf * 16 + lr, kk * 4 + g);

  // QK^T for all active c-groups (independent MFMAs -> ILP)
  f32x4 st[NC][4];
#pragma unroll
  for (int c = 0; c < NC; ++c) {
    int cc = (NC == 2) ? c : 1;
#pragma unroll
    for (int i = 0; i < 4; ++i) {
      f32x4 z = {};
      z = mma16(kf[i][0], qf[cc][0], z);
      z = mma16(kf[i][1], qf[cc][1], z);
      st[c][i] = z;
    }
  }

  // online softmax in exp2 domain, both chains interleaved
  const float SC = 0.125f * 1.44269504f;
  float p[NC][16], pm[NC], corr[NC];
#pragma unroll
  for (int c = 0; c < NC; ++c) {
    int cc = (NC == 2) ? c : 1;
    bool band = (cc == 0) ? band0 : band1;
    int qgc = ((cc == 0) ? qb0 : qb1) + lr;
    float m_ = -INFINITY;
#pragma unroll
    for (int i = 0; i < 4; ++i)
#pragma unroll
      for (int r = 0; r < 4; ++r) {
        float v = st[c][i][r] * SC;
        if (band) {
          int key = kv0 + i * 16 + g * 4 + r;
          if (key > qgc) v = -INFINITY;
        }
        p[c][i * 4 + r] = v;
        m_ = fmaxf(m_, v);
      }
    pm[c] = m_;
  }
#pragma unroll
  for (int c = 0; c < NC; ++c) pm[c] = fmaxf(pm[c], __shfl_xor(pm[c], 16));
#pragma unroll
  for (int c = 0; c < NC; ++c) pm[c] = fmaxf(pm[c], __shfl_xor(pm[c], 32));
  float dsum[NC];
#pragma unroll
  for (int c = 0; c < NC; ++c) {
    int cc = (NC == 2) ? c : 1;
    float nm = fmaxf(mrow[cc], pm[c]);
    corr[c] = exp2f(mrow[cc] - nm);
    mrow[cc] = nm;
    float ds_ = 0.0f;
#pragma unroll
    for (int kx = 0; kx < 16; ++kx) {
      float pv = exp2f(p[c][kx] - nm);
      p[c][kx] = pv;
      ds_ += pv;
    }
    dsum[c] = ds_;
  }
#pragma unroll
  for (int c = 0; c < NC; ++c) dsum[c] += __shfl_xor(dsum[c], 16);
#pragma unroll
  for (int c = 0; c < NC; ++c) dsum[c] += __shfl_xor(dsum[c], 32);
#pragma unroll
  for (int c = 0; c < NC; ++c) {
    int cc = (NC == 2) ? c : 1;
    dden[cc] = dden[cc] * corr[c] + dsum[c];
  }

  // rescale acc + write P to swizzled per-wave LDS
#pragma unroll
  for (int c = 0; c < NC; ++c) {
    int cc = (NC == 2) ? c : 1;
#pragma unroll
    for (int r = 0; r < 4; ++r) {
      float cr = __shfl(corr[c], g * 4 + r);
#pragma unroll
      for (int jf = 0; jf < 4; ++jf) acc[cc][jf][r] *= cr;
    }
    int prow = cc * 16 + lr;
#pragma unroll
    for (int i = 0; i < 4; ++i) {
      uint2 pk;
      pk.x = pack2(p[c][i * 4 + 0], p[c][i * 4 + 1]);
      pk.y = pack2(p[c][i * 4 + 2], p[c][i * 4 + 3]);
      int seg = (i * 2 + (g >> 1)) ^ (prow & 7);
      *(uint2*)(pw + prow * 64 + seg * 8 + (g & 1) * 4) = pk;
    }
  }

  // PV: out[q, dh] += P[q, key] * V^T[dh, key]
#pragma unroll
  for (int c = 0; c < NC; ++c) {
    int cc = (NC == 2) ? c : 1;
    int prow = cc * 16 + lr;
#pragma unroll
    for (int kk = 0; kk < 2; ++kk) {
      bf16x8 pa = *(const bf16x8*)(pw + prow * 64 + (((kk * 4 + g) ^ (prow & 7)) << 3));
#pragma unroll
      for (int jf = 0; jf < 4; ++jf)
        acc[cc][jf] = mma16(pa, vb[kk][jf], acc[cc][jf]);
    }
  }
}

__global__ __launch_bounds__(256, 2) void k_attn(const short* __restrict__ q_b,
                                                 const short* __restrict__ k_b,
                                                 const short* __restrict__ vT_b,
                                                 short* __restrict__ o_b) {
  __shared__ short Ks[3][64 * 64];   // 24 KB
  __shared__ short VTs[3][64 * 64];  // 24 KB
  __shared__ short Ps[4][32 * 64];   // 16 KB
  int tid = threadIdx.x;
  int w = tid >> 6, l = tid & 63;
  int lr = l & 15, g = l >> 4;
  int ib = blockIdx.x, bh = blockIdx.y;
  int qlo = ib, qhi = 31 - ib;
  int qb0 = qlo * 64 + w * 16;  // wave q base, c=0
  int qb1 = qhi * 64 + w * 16;  // wave q base, c=1

  // Q fragments (B-operand: n-row = q = qb_c + lr, k-elems = kk*32 + g*8)
  bf16x8 qf[2][2];
  const short* Qg = q_b + (size_t)bh * 2048 * 64;
#pragma unroll
  for (int kk = 0; kk < 2; ++kk) {
    qf[0][kk] = *(const bf16x8*)(Qg + (size_t)(qb0 + lr) * 64 + kk * 32 + g * 8);
    qf[1][kk] = *(const bf16x8*)(Qg + (size_t)(qb1 + lr) * 64 + kk * 32 + g * 8);
  }

  f32x4 acc[2][4] = {};
  float mrow[2] = {-INFINITY, -INFINITY};
  float dden[2] = {0.0f, 0.0f};
  int nt = qhi + 1;  // >= 17
  const short* Kg = k_b + (size_t)bh * 2048 * 64;
  const short* Vg = vT_b + (size_t)bh * 64 * 2048;
  short* pw = &Ps[w][0];

  // prologue: stage tiles 0 and 1 (4 loads/thread each)
  stage_swz<64>(Kg, 64, &Ks[0][0], tid);
  stage_swz<64>(Vg, 2048, &VTs[0][0], tid);
  stage_swz<64>(Kg + 64 * 64, 64, &Ks[1][0], tid);
  stage_swz<64>(Vg + 64, 2048, &VTs[1][0], tid);

  // Phase A: kt in [0, qlo] -> both c-groups
#pragma unroll 1
  for (int kt = 0; kt <= qlo; ++kt) {
    VMCNT(4);  // wait tile kt's 4 loads; tile kt+1's stay in flight
    BARF();
    if (kt + 2 < nt) {
      int sl = (kt + 2) % 3;
      stage_swz<64>(Kg + (size_t)(kt + 2) * 64 * 64, 64, &Ks[sl][0], tid);
      stage_swz<64>(Vg + (kt + 2) * 64, 2048, &VTs[sl][0], tid);
    }
    int s = kt % 3;
    attn_tile<2>(&Ks[s][0], &VTs[s][0], pw, qf, acc, mrow, dden,
                 kt * 64, qb0, qb1, kt == qlo, false, lr, g);
  }
  // Phase B: kt in (qlo, qhi] -> only c=1
#pragma unroll 1
  for (int kt = qlo + 1; kt < nt; ++kt) {
    VMCNT(4);
    BARF();
    if (kt + 2 < nt) {
      int sl = (kt + 2) % 3;
      stage_swz<64>(Kg + (size_t)(kt + 2) * 64 * 64, 64, &Ks[sl][0], tid);
      stage_swz<64>(Vg + (kt + 2) * 64, 2048, &VTs[sl][0], tid);
    }
    int s = kt % 3;
    attn_tile<1>(&Ks[s][0], &VTs[s][0], pw, qf, acc, mrow, dden,
                 kt * 64, qb0, qb1, false, kt == qhi, lr, g);
  }

  // epilogue: D col = dh-within = lr, row = q-within-16 = g*4 + r
  int hh = bh & 15, b_ = bh >> 4;
#pragma unroll
  for (int c = 0; c < 2; ++c) {
    int qbc = (c == 0) ? qb0 : qb1;
#pragma unroll
    for (int r = 0; r < 4; ++r) {
      float dq = __shfl(dden[c], g * 4 + r);
      float inv = 1.0f / dq;
      int mg = qbc + g * 4 + r;
      size_t rowoff = ((size_t)b_ * 2048 + mg) * 1024 + hh * 64;
#pragma unroll
      for (int jf = 0; jf < 4; ++jf)
        o_b[rowoff + jf * 16 + lr] = f2b(acc[c][jf][r] * inv);
    }
  }
}

// ---------------------------------------------------------------------------
// Launch
// ---------------------------------------------------------------------------
extern "C" void kernel_launch(void* const* d_in, const int* in_sizes, int n_in,
                              void* d_out, int out_size, void* d_ws, size_t ws_size,
                              hipStream_t stream) {
  const float* x     = (const float*)d_in[0];
  const float* wn1   = (const float*)d_in[1];
  const float* wqkv  = (const float*)d_in[2];
  const float* wproj = (const float*)d_in[3];
  const float* wn2   = (const float*)d_in[4];
  const float* wgate = (const float*)d_in[5];
  const float* wup   = (const float*)d_in[6];
  const float* wdown = (const float*)d_in[7];
  float* out = (float*)d_out;
  char* ws = (char*)d_ws;

  short* wqkv_b  = (short*)(ws + 0);         //  6 MB
  short* wproj_b = (short*)(ws + 6291456);   //  2 MB
  short* wgate_b = (short*)(ws + 8388608);   //  8 MB
  short* wup_b   = (short*)(ws + 16777216);  //  8 MB
  short* wdown_b = (short*)(ws + 25165824);  //  8 MB
  short* h_b     = (short*)(ws + 33554432);  //  8 MB (h, then h2)
  short* q_b     = (short*)(ws + 41943040);  //  8 MB
  short* k_b     = (short*)(ws + 50331648);  //  8 MB
  short* vT_b    = (short*)(ws + 58720256);  //  8 MB
  short* ao_b    = (short*)(ws + 67108864);  //  8 MB
  short* act_b   = q_b;   // 32 MB alias over q/k/vT/ao (free after attention)
  float* x1 = out;
  float* kc = out + 4194304;
  float* vc = out + 8388608;

  k_cvt_all<<<16384, 256, 0, stream>>>(wqkv, wqkv_b, wproj, wproj_b,
                                       wgate, wgate_b, wup, wup_b, wdown, wdown_b);

  k_rms<<<4096, 256, 0, stream>>>(x, wn1, h_b);

  // q,k,v = h @ {Wq,Wk,Wv}^T — triple-B fused, grid 256 = 1 block/CU
  k_qkv<<<256, 512, 0, stream>>>(h_b, wqkv_b, q_b, k_b, vT_b, kc, vc);

  k_attn<<<dim3(16, 32), 256, 0, stream>>>(q_b, k_b, vT_b, ao_b);

  // x1 = x + attn @ w_proj^T  (grid 16x16 = 256 blocks, 256x64 tiles)
  k_gemm_skinny<<<256, 256, 0, stream>>>(ao_b, wproj_b, 4096, 1024, 1024, 16,
                                         x, x1);

  k_rms<<<4096, 256, 0, stream>>>(x1, wn2, h_b);

  // act = silu(h2 @ w_gate^T) * (h2 @ w_up^T)  — fused N-walk, grid 256
  k_mlp<<<256, 512, 0, stream>>>(h_b, wgate_b, wup_b, act_b);

  // x_out = x1 + act @ w_down^T  (grid 16x16 = 256 blocks)
  k_gemm_skinny<<<256, 256, 0, stream>>>(act_b, wdown_b, 4096, 1024, 4096, 16,
                                         x1, out);
}

// Round 14
// 275.789 us; speedup vs baseline: 1.1557x; 1.1557x over previous
//
#include <hip/hip_runtime.h>
#include <hip/hip_bf16.h>
#include <cstdint>
#include <cstddef>

// B=2, T=2048, D=1024, H=16, DH=64, CTX=2048.  M = B*T = 4096.

using bf16x8 = __attribute__((ext_vector_type(8))) __bf16;
using f32x4  = __attribute__((ext_vector_type(4))) float;

#define VMCNT(n) asm volatile("s_waitcnt vmcnt(" #n ")" ::: "memory")
#define LGKM0()  do { asm volatile("s_waitcnt lgkmcnt(0)" ::: "memory"); \
                      __builtin_amdgcn_sched_barrier(0); } while (0)
#define BARF()   do { asm volatile("" ::: "memory"); __builtin_amdgcn_s_barrier(); \
                      asm volatile("" ::: "memory"); } while (0)

__device__ __forceinline__ short f2b(float f) {
  uint32_t u = __builtin_bit_cast(uint32_t, f);
  uint32_t r = (u + 0x7FFFu + ((u >> 16) & 1u)) >> 16;
  return (short)r;
}
__device__ __forceinline__ float b2f(short s) {
  uint32_t u = ((uint32_t)(uint16_t)s) << 16;
  return __builtin_bit_cast(float, u);
}
// truncation pack of two f32 -> two bf16 in a u32 (P values in [0,1]; bias <0.4%)
__device__ __forceinline__ uint32_t pack2(float a, float b) {
  return (__builtin_bit_cast(uint32_t, a) >> 16) |
         (__builtin_bit_cast(uint32_t, b) & 0xFFFF0000u);
}

__device__ __forceinline__ void gload16(const short* g, short* l) {
  __builtin_amdgcn_global_load_lds(
      (const __attribute__((address_space(1))) void*)g,
      (__attribute__((address_space(3))) void*)l, 16, 0, 0);
}

// ---------------------------------------------------------------------------
// Staging, 64-col (128B) rows, XOR (row&7) swizzle applied on GLOBAL source,
// linear LDS dest (global_load_lds requirement).  Zero-bank-conflict verified.
// ---------------------------------------------------------------------------
template<int ROWS>  // 256 threads, ROWS/32 loads per thread
__device__ __forceinline__ void stage_swz(const short* __restrict__ g, int ldg,
                                          short* lds, int tid) {
#pragma unroll
  for (int jj = 0; jj < ROWS / 32; ++jj) {
    int row = jj * 32 + (tid >> 3);
    int seg = tid & 7;
    gload16(g + (size_t)row * ldg + ((seg ^ (row & 7)) << 3),
            lds + row * 64 + (seg << 3));
  }
}

// 512 threads, one 64-row round per call (1 gload16/thread)
__device__ __forceinline__ void stage_round512(const short* __restrict__ g, int ldg,
                                               short* lds, int tid, int rbase) {
  int row = rbase + (tid >> 3);
  int seg = tid & 7;
  gload16(g + (size_t)row * ldg + ((seg ^ (row & 7)) << 3),
          lds + row * 64 + (seg << 3));
}

__device__ __forceinline__ bf16x8 frag64(const short* lds, int row, int seg) {
  return *(const bf16x8*)(lds + row * 64 + ((seg ^ (row & 7)) << 3));
}

__device__ __forceinline__ f32x4 mma16(bf16x8 a, bf16x8 b, f32x4 c) {
  return __builtin_amdgcn_mfma_f32_16x16x32_bf16(a, b, c, 0, 0, 0);
}

// ---------------------------------------------------------------------------
// Fused weight conversion f32 -> bf16
// ---------------------------------------------------------------------------
__global__ void k_cvt_all(const float* __restrict__ wqkv, short* __restrict__ oqkv,
                          const float* __restrict__ wproj, short* __restrict__ oproj,
                          const float* __restrict__ wgate, short* __restrict__ ogate,
                          const float* __restrict__ wup, short* __restrict__ oup,
                          const float* __restrict__ wdown, short* __restrict__ odown) {
  int bid = blockIdx.x;
  const float* src;
  short* dst;
  int off;
  if (bid < 3072)       { src = wqkv;  dst = oqkv;  off = bid; }
  else if (bid < 4096)  { src = wproj; dst = oproj; off = bid - 3072; }
  else if (bid < 8192)  { src = wgate; dst = ogate; off = bid - 4096; }
  else if (bid < 12288) { src = wup;   dst = oup;   off = bid - 8192; }
  else                  { src = wdown; dst = odown; off = bid - 12288; }
  int i = off * 256 + threadIdx.x;
  float4 v = ((const float4*)src)[i];
  ((short4*)dst)[i] = make_short4(f2b(v.x), f2b(v.y), f2b(v.z), f2b(v.w));
}

// ---------------------------------------------------------------------------
// RMSNorm: one block (256 thr) per row of 1024 f32 -> bf16
// ---------------------------------------------------------------------------
__global__ void k_rms(const float* __restrict__ x, const float* __restrict__ w,
                      short* __restrict__ out) {
  int row = blockIdx.x;
  int tid = threadIdx.x;
  float4 v = *(const float4*)(x + (size_t)row * 1024 + tid * 4);
  float ss = v.x * v.x + v.y * v.y + v.z * v.z + v.w * v.w;
#pragma unroll
  for (int o = 1; o < 64; o <<= 1) ss += __shfl_xor(ss, o);
  __shared__ float sred[4];
  int wid = tid >> 6, lane = tid & 63;
  if (lane == 0) sred[wid] = ss;
  __syncthreads();
  float tot = sred[0] + sred[1] + sred[2] + sred[3];
  float r = rsqrtf(tot * (1.0f / 1024.0f) + 1e-6f);
  float4 wv = *(const float4*)(w + tid * 4);
  short4 o = make_short4(f2b(v.x * r * wv.x), f2b(v.y * r * wv.y),
                         f2b(v.z * r * wv.z), f2b(v.w * r * wv.w));
  *(short4*)(out + (size_t)row * 1024 + tid * 4) = o;
}

// ---------------------------------------------------------------------------
// QKV triple-B kernel: q,k,v = A @ {Wq,Wk,Wv}^T share the A tile.
// BM=128, BN=128 per operand, BK=64, 8 waves.  Grid 256 = 1 block/CU.
// ---------------------------------------------------------------------------
__global__ __launch_bounds__(512) void k_qkv(
    const short* __restrict__ A, const short* __restrict__ W,
    short* __restrict__ q_b, short* __restrict__ k_b, short* __restrict__ vT_b,
    float* __restrict__ kc, float* __restrict__ vc) {
  const int K = 1024, nk = 16;
  __shared__ short As[2][128 * 64];  // 32 KB
  __shared__ short Bq[2][128 * 64];  // 32 KB
  __shared__ short Bk[2][128 * 64];  // 32 KB
  __shared__ short Bv[2][128 * 64];  // 32 KB
  int tid = threadIdx.x;
  int bid = blockIdx.x;
  int swz = (bid & 7) * 32 + (bid >> 3);  // nwg = 256
  int bx = swz & 7, by = swz >> 3;
  int m0 = by * 128, n0 = bx * 128;
  int w = tid >> 6, l = tid & 63;
  int wr = w >> 2, wc = w & 3;
  int lr = l & 15, lseg = l >> 4;
  f32x4 aq[4][2] = {}, ak[4][2] = {}, av[4][2] = {};
  const short* Ab = A + (size_t)m0 * K;
  const short* Qb = W + (size_t)n0 * K;
  const short* Kb = W + (size_t)(1024 + n0) * K;
  const short* Vb = W + (size_t)(2048 + n0) * K;

  // prologue: tile0 all operands (8 loads) + A(1) (2 loads, newest)
  stage_round512(Ab, K, &As[0][0], tid, 0);
  stage_round512(Ab, K, &As[0][0], tid, 64);
  stage_round512(Qb, K, &Bq[0][0], tid, 0);
  stage_round512(Qb, K, &Bq[0][0], tid, 64);
  stage_round512(Kb, K, &Bk[0][0], tid, 0);
  stage_round512(Kb, K, &Bk[0][0], tid, 64);
  stage_round512(Vb, K, &Bv[0][0], tid, 0);
  stage_round512(Vb, K, &Bv[0][0], tid, 64);
  stage_round512(Ab + 64, K, &As[1][0], tid, 0);
  stage_round512(Ab + 64, K, &As[1][0], tid, 64);

  bf16x8 a[4][2], b[2][2];
#pragma unroll 2
  for (int t = 0; t < nk; ++t) {
    short* Sa = &As[t & 1][0];
    short* Sq = &Bq[t & 1][0];
    short* Sk = &Bk[t & 1][0];
    short* Sv = &Bv[t & 1][0];
    short* SqN = &Bq[(t + 1) & 1][0];
    short* SkN = &Bk[(t + 1) & 1][0];
    short* SvN = &Bv[(t + 1) & 1][0];
    const short* Ag2 = Ab + (size_t)(t + 2) * 64;
    const short* Qg1 = Qb + (size_t)(t + 1) * 64;
    const short* Kg1 = Kb + (size_t)(t + 1) * 64;
    const short* Vg1 = Vb + (size_t)(t + 1) * 64;
    bool pf1 = (t + 1 < nk), pf2 = (t + 2 < nk);

    // boundary: tile t resident; keep A(t+2)'s 2 loads in flight
    VMCNT(2);
    BARF();

    // -- P1: q.  reads a(8) + bq(4); stage Bq(t+1), Bk(t+1)
#pragma unroll
    for (int i = 0; i < 4; ++i)
#pragma unroll
      for (int kk = 0; kk < 2; ++kk)
        a[i][kk] = frag64(Sa, wr * 64 + i * 16 + lr, kk * 4 + lseg);
#pragma unroll
    for (int j = 0; j < 2; ++j)
#pragma unroll
      for (int kk = 0; kk < 2; ++kk)
        b[j][kk] = frag64(Sq, wc * 32 + j * 16 + lr, kk * 4 + lseg);
    if (pf1) {
      stage_round512(Qg1, K, SqN, tid, 0);
      stage_round512(Qg1, K, SqN, tid, 64);
      stage_round512(Kg1, K, SkN, tid, 0);
      stage_round512(Kg1, K, SkN, tid, 64);
    }
    BARF();
    LGKM0();
    __builtin_amdgcn_s_setprio(1);
#pragma unroll
    for (int i = 0; i < 4; ++i)
#pragma unroll
      for (int j = 0; j < 2; ++j) {
        aq[i][j] = mma16(a[i][0], b[j][0], aq[i][j]);
        aq[i][j] = mma16(a[i][1], b[j][1], aq[i][j]);
      }
    __builtin_amdgcn_s_setprio(0);

    // -- P2: k.  reads bk(4); stage Bv(t+1)
#pragma unroll
    for (int j = 0; j < 2; ++j)
#pragma unroll
      for (int kk = 0; kk < 2; ++kk)
        b[j][kk] = frag64(Sk, wc * 32 + j * 16 + lr, kk * 4 + lseg);
    if (pf1) {
      stage_round512(Vg1, K, SvN, tid, 0);
      stage_round512(Vg1, K, SvN, tid, 64);
    }
    BARF();
    LGKM0();
    __builtin_amdgcn_s_setprio(1);
#pragma unroll
    for (int i = 0; i < 4; ++i)
#pragma unroll
      for (int j = 0; j < 2; ++j) {
        ak[i][j] = mma16(a[i][0], b[j][0], ak[i][j]);
        ak[i][j] = mma16(a[i][1], b[j][1], ak[i][j]);
      }
    __builtin_amdgcn_s_setprio(0);

    // -- P3: v.  reads bv(4); stage A(t+2) -> Sa (a-reads done since BARF2)
#pragma unroll
    for (int j = 0; j < 2; ++j)
#pragma unroll
      for (int kk = 0; kk < 2; ++kk)
        b[j][kk] = frag64(Sv, wc * 32 + j * 16 + lr, kk * 4 + lseg);
    if (pf2) {
      stage_round512(Ag2, K, Sa, tid, 0);
      stage_round512(Ag2, K, Sa, tid, 64);
    }
    BARF();
    LGKM0();
    __builtin_amdgcn_s_setprio(1);
#pragma unroll
    for (int i = 0; i < 4; ++i)
#pragma unroll
      for (int j = 0; j < 2; ++j) {
        av[i][j] = mma16(a[i][0], b[j][0], av[i][j]);
        av[i][j] = mma16(a[i][1], b[j][1], av[i][j]);
      }
    __builtin_amdgcn_s_setprio(0);
  }

  // epilogue: frag col = lr (n), row = lseg*4 + r (m)
#pragma unroll
  for (int i = 0; i < 4; ++i) {
#pragma unroll
    for (int j = 0; j < 2; ++j) {
#pragma unroll
      for (int r = 0; r < 4; ++r) {
        int m = m0 + wr * 64 + i * 16 + lseg * 4 + r;
        int n = n0 + wc * 32 + j * 16 + lr;
        int hh = n >> 6, dh = n & 63;
        int b_ = m >> 11, tt = m & 2047;
        int bh = b_ * 16 + hh;
        size_t idx = ((size_t)bh * 2048 + tt) * 64 + dh;
        q_b[idx] = f2b(aq[i][j][r]);
        float fk = ak[i][j][r];
        k_b[idx] = f2b(fk);
        kc[idx] = fk;
        float fv = av[i][j][r];
        vT_b[((size_t)bh * 64 + dh) * 2048 + tt] = f2b(fv);
        vc[idx] = fv;
      }
    }
  }
}

// ---------------------------------------------------------------------------
// Fused MLP gate+up: act = silu(A@Wg^T) * (A@Wu^T), A=[4096,1024] bf16.
// Tile 256(M) x 128(N), BK=64, 8 waves; 4 phases/K-tile; vmcnt(4) boundary.
// XCD partition: XCD j owns bx in [4j, 4j+4) x all 16 by (bx-fast order):
// per-XCD B working set = 4 x 0.5 MB = 2 MB (L2-resident) -> B fetched once
// globally (16 MB) instead of once per XCD (128 MB).
// ---------------------------------------------------------------------------
__global__ __launch_bounds__(512) void k_mlp(
    const short* __restrict__ A, const short* __restrict__ Wg,
    const short* __restrict__ Wu, short* __restrict__ outb) {
  const int K = 1024, N = 4096, nk = 16;
  __shared__ short As[2][256 * 64];  // 64 KB
  __shared__ short Bg[2][128 * 64];  // 32 KB
  __shared__ short Bu[2][128 * 64];  // 32 KB
  int tid = threadIdx.x;
  int bid = blockIdx.x;
  // XCD-local partition (grid 512, 64 blocks/XCD): bx = xcd*4 + (idx&3)
  int xcd = bid & 7, idx = bid >> 3;
  int bx = xcd * 4 + (idx & 3);
  int by = idx >> 2;
  int m0 = by * 256, n0 = bx * 128;
  int w = tid >> 6, l = tid & 63;
  int wr = w >> 2, wc = w & 3;
  int lr = l & 15, lseg = l >> 4;
  f32x4 aG[2][4][2] = {}, aU[2][4][2] = {};  // [qm][i][j]
  const short* Ab = A + (size_t)m0 * K;
  const short* Gb = Wg + (size_t)n0 * K;
  const short* Ub = Wu + (size_t)n0 * K;

  // prologue: A(0)x4, Bg(0)x2, Bu(0)x2, A(1)x4  (A(1) newest for vmcnt(4))
  stage_round512(Ab, K, &As[0][0], tid, 0);
  stage_round512(Ab, K, &As[0][0], tid, 64);
  stage_round512(Ab, K, &As[0][0], tid, 128);
  stage_round512(Ab, K, &As[0][0], tid, 192);
  stage_round512(Gb, K, &Bg[0][0], tid, 0);
  stage_round512(Gb, K, &Bg[0][0], tid, 64);
  stage_round512(Ub, K, &Bu[0][0], tid, 0);
  stage_round512(Ub, K, &Bu[0][0], tid, 64);
  stage_round512(Ab + 64, K, &As[1][0], tid, 0);
  stage_round512(Ab + 64, K, &As[1][0], tid, 64);
  stage_round512(Ab + 64, K, &As[1][0], tid, 128);
  stage_round512(Ab + 64, K, &As[1][0], tid, 192);

  bf16x8 a0[4][2], a1[4][2], bg[2][2], bu[2][2];
#pragma unroll 2
  for (int t = 0; t < nk; ++t) {
    short* Sa  = &As[t & 1][0];
    short* Sg  = &Bg[t & 1][0];
    short* Su  = &Bu[t & 1][0];
    short* SgN = &Bg[(t + 1) & 1][0];
    short* SuN = &Bu[(t + 1) & 1][0];
    const short* Ag2 = Ab + (size_t)(t + 2) * 64;
    const short* Gg1 = Gb + (size_t)(t + 1) * 64;
    const short* Ug1 = Ub + (size_t)(t + 1) * 64;
    bool pf1 = (t + 1 < nk), pf2 = (t + 2 < nk);

    // boundary: tile t resident; keep A(t+1)x4 in flight
    VMCNT(4);
    BARF();

    // -- P1: gate.qm0
#pragma unroll
    for (int i = 0; i < 4; ++i)
#pragma unroll
      for (int kk = 0; kk < 2; ++kk)
        a0[i][kk] = frag64(Sa, wr * 128 + i * 16 + lr, kk * 4 + lseg);
#pragma unroll
    for (int j = 0; j < 2; ++j)
#pragma unroll
      for (int kk = 0; kk < 2; ++kk)
        bg[j][kk] = frag64(Sg, wc * 32 + j * 16 + lr, kk * 4 + lseg);
    if (pf1) {
      stage_round512(Gg1, K, SgN, tid, 0);
      stage_round512(Gg1, K, SgN, tid, 64);
      stage_round512(Ug1, K, SuN, tid, 0);
      stage_round512(Ug1, K, SuN, tid, 64);
    }
    BARF();
    LGKM0();
    __builtin_amdgcn_s_setprio(1);
#pragma unroll
    for (int i = 0; i < 4; ++i)
#pragma unroll
      for (int j = 0; j < 2; ++j) {
        aG[0][i][j] = mma16(a0[i][0], bg[j][0], aG[0][i][j]);
        aG[0][i][j] = mma16(a0[i][1], bg[j][1], aG[0][i][j]);
      }
    __builtin_amdgcn_s_setprio(0);

    // -- P2: up.qm0 (reuse a0)
#pragma unroll
    for (int j = 0; j < 2; ++j)
#pragma unroll
      for (int kk = 0; kk < 2; ++kk)
        bu[j][kk] = frag64(Su, wc * 32 + j * 16 + lr, kk * 4 + lseg);
    if (pf2) {
      stage_round512(Ag2, K, Sa, tid, 0);
      stage_round512(Ag2, K, Sa, tid, 128);
    }
    BARF();
    LGKM0();
    __builtin_amdgcn_s_setprio(1);
#pragma unroll
    for (int i = 0; i < 4; ++i)
#pragma unroll
      for (int j = 0; j < 2; ++j) {
        aU[0][i][j] = mma16(a0[i][0], bu[j][0], aU[0][i][j]);
        aU[0][i][j] = mma16(a0[i][1], bu[j][1], aU[0][i][j]);
      }
    __builtin_amdgcn_s_setprio(0);

    // -- P3: gate.qm1 (reuse bg)
#pragma unroll
    for (int i = 0; i < 4; ++i)
#pragma unroll
      for (int kk = 0; kk < 2; ++kk)
        a1[i][kk] = frag64(Sa, wr * 128 + 64 + i * 16 + lr, kk * 4 + lseg);
    BARF();
    LGKM0();
    __builtin_amdgcn_s_setprio(1);
#pragma unroll
    for (int i = 0; i < 4; ++i)
#pragma unroll
      for (int j = 0; j < 2; ++j) {
        aG[1][i][j] = mma16(a1[i][0], bg[j][0], aG[1][i][j]);
        aG[1][i][j] = mma16(a1[i][1], bg[j][1], aG[1][i][j]);
      }
    __builtin_amdgcn_s_setprio(0);

    // -- P4: up.qm1 (reuse a1, bu); stage A(t+2) r1,r3 (rows read at P3)
    if (pf2) {
      stage_round512(Ag2, K, Sa, tid, 64);
      stage_round512(Ag2, K, Sa, tid, 192);
    }
    BARF();
    __builtin_amdgcn_s_setprio(1);
#pragma unroll
    for (int i = 0; i < 4; ++i)
#pragma unroll
      for (int j = 0; j < 2; ++j) {
        aU[1][i][j] = mma16(a1[i][0], bu[j][0], aU[1][i][j]);
        aU[1][i][j] = mma16(a1[i][1], bu[j][1], aU[1][i][j]);
      }
    __builtin_amdgcn_s_setprio(0);
  }

  // epilogue: act = silu(g) * u, bf16
#pragma unroll
  for (int qm = 0; qm < 2; ++qm) {
#pragma unroll
    for (int i = 0; i < 4; ++i) {
#pragma unroll
      for (int j = 0; j < 2; ++j) {
#pragma unroll
        for (int r = 0; r < 4; ++r) {
          int m = m0 + wr * 128 + qm * 64 + i * 16 + lseg * 4 + r;
          int n = n0 + wc * 32 + j * 16 + lr;
          float g = aG[qm][i][j][r];
          float u = aU[qm][i][j][r];
          float s = g / (1.0f + __expf(-g));
          outb[(size_t)m * N + n] = f2b(s * u);
        }
      }
    }
  }
}

// ---------------------------------------------------------------------------
// Skinny GEMM (round-12 version): 128x64 tile, BK=64, ring-3, 4 waves
// (2M x 2N, wave 64x32).  outf[m,n] = C + res[m,n]  (proj, down; grid 512)
// ---------------------------------------------------------------------------
__global__ __launch_bounds__(256, 2) void k_gemm_skinny(
    const short* __restrict__ A, const short* __restrict__ Bw,
    int M, int N, int K, int gx,
    const float* __restrict__ res, float* __restrict__ outf) {
  __shared__ short As[3][128 * 64];  // 48 KB
  __shared__ short Bs[3][64 * 64];   // 24 KB
  int tid = threadIdx.x;
  int nwg = gridDim.x, bid = blockIdx.x;
  int swz = (bid & 7) * (nwg >> 3) + (bid >> 3);
  int bx = swz % gx, by = swz / gx;
  int m0 = by * 128, n0 = bx * 64;
  int w = tid >> 6, l = tid & 63;
  int wr = w >> 1, wc = w & 1;
  int lr = l & 15, lseg = l >> 4;
  f32x4 acc[4][2] = {};
  int nk = K >> 6;
  const short* Ab = A + (size_t)m0 * K;
  const short* Bb = Bw + (size_t)n0 * K;

  stage_swz<128>(Ab, K, &As[0][0], tid);
  stage_swz<64>(Bb, K, &Bs[0][0], tid);
  stage_swz<128>(Ab + 64, K, &As[1][0], tid);
  stage_swz<64>(Bb + 64, K, &Bs[1][0], tid);

#pragma unroll 1
  for (int u = 0; u < nk; ++u) {
    VMCNT(6);   // tiles u+1, u+2 may stay in flight (6 loads/tile)
    BARF();
    if (u + 2 < nk) {
      int sl = (u + 2) % 3;
      stage_swz<128>(Ab + (u + 2) * 64, K, &As[sl][0], tid);
      stage_swz<64>(Bb + (u + 2) * 64, K, &Bs[sl][0], tid);
    }
    const short* Asl = &As[u % 3][0];
    const short* Bsl = &Bs[u % 3][0];
    bf16x8 ar[4][2], br[2][2];
#pragma unroll
    for (int i = 0; i < 4; ++i)
#pragma unroll
      for (int kk = 0; kk < 2; ++kk)
        ar[i][kk] = frag64(Asl, wr * 64 + i * 16 + lr, kk * 4 + lseg);
#pragma unroll
    for (int j = 0; j < 2; ++j)
#pragma unroll
      for (int kk = 0; kk < 2; ++kk)
        br[j][kk] = frag64(Bsl, wc * 32 + j * 16 + lr, kk * 4 + lseg);
    LGKM0();
    __builtin_amdgcn_s_setprio(1);
#pragma unroll
    for (int i = 0; i < 4; ++i)
#pragma unroll
      for (int j = 0; j < 2; ++j) {
        acc[i][j] = mma16(ar[i][0], br[j][0], acc[i][j]);
        acc[i][j] = mma16(ar[i][1], br[j][1], acc[i][j]);
      }
    __builtin_amdgcn_s_setprio(0);
  }

#pragma unroll
  for (int i = 0; i < 4; ++i) {
#pragma unroll
    for (int j = 0; j < 2; ++j) {
#pragma unroll
      for (int r = 0; r < 4; ++r) {
        int m = m0 + wr * 64 + i * 16 + (l >> 4) * 4 + r;
        int n = n0 + wc * 32 + j * 16 + lr;
        outf[(size_t)m * N + n] = acc[i][j][r] + res[(size_t)m * N + n];
      }
    }
  }
}

// ---------------------------------------------------------------------------
// Causal flash attention v4 — balanced pairing + ring-3 counted-vmcnt
// prefetch + interleaved c-groups via phase-split loops.
// ---------------------------------------------------------------------------
template<int NC>
__device__ __forceinline__ void attn_tile(
    const short* __restrict__ Ksl, const short* __restrict__ Vsl,
    short* __restrict__ pw,
    const bf16x8 (&qf)[2][2], f32x4 (&acc)[2][4],
    float (&mrow)[2], float (&dden)[2],
    int kv0, int qb0, int qb1, bool band0, bool band1,
    int lr, int g) {
  // hoisted K and V fragments (shared across c-groups)
  bf16x8 kf[4][2], vb[2][4];
#pragma unroll
  for (int i = 0; i < 4; ++i)
#pragma unroll
    for (int kk = 0; kk < 2; ++kk)
      kf[i][kk] = frag64(Ksl, i * 16 + lr, kk * 4 + g);
#pragma unroll
  for (int kk = 0; kk < 2; ++kk)
#pragma unroll
    for (int jf = 0; jf < 4; ++jf)
      vb[kk][jf] = frag64(Vsl, jf * 16 + lr, kk * 4 + g);

  // QK^T for all active c-groups (independent MFMAs -> ILP)
  f32x4 st[NC][4];
#pragma unroll
  for (int c = 0; c < NC; ++c) {
    int cc = (NC == 2) ? c : 1;
#pragma unroll
    for (int i = 0; i < 4; ++i) {
      f32x4 z = {};
      z = mma16(kf[i][0], qf[cc][0], z);
      z = mma16(kf[i][1], qf[cc][1], z);
      st[c][i] = z;
    }
  }

  // online softmax in exp2 domain, both chains interleaved
  const float SC = 0.125f * 1.44269504f;
  float p[NC][16], pm[NC], corr[NC];
#pragma unroll
  for (int c = 0; c < NC; ++c) {
    int cc = (NC == 2) ? c : 1;
    bool band = (cc == 0) ? band0 : band1;
    int qgc = ((cc == 0) ? qb0 : qb1) + lr;
    float m_ = -INFINITY;
#pragma unroll
    for (int i = 0; i < 4; ++i)
#pragma unroll
      for (int r = 0; r < 4; ++r) {
        float v = st[c][i][r] * SC;
        if (band) {
          int key = kv0 + i * 16 + g * 4 + r;
          if (key > qgc) v = -INFINITY;
        }
        p[c][i * 4 + r] = v;
        m_ = fmaxf(m_, v);
      }
    pm[c] = m_;
  }
#pragma unroll
  for (int c = 0; c < NC; ++c) pm[c] = fmaxf(pm[c], __shfl_xor(pm[c], 16));
#pragma unroll
  for (int c = 0; c < NC; ++c) pm[c] = fmaxf(pm[c], __shfl_xor(pm[c], 32));
  float dsum[NC];
#pragma unroll
  for (int c = 0; c < NC; ++c) {
    int cc = (NC == 2) ? c : 1;
    float nm = fmaxf(mrow[cc], pm[c]);
    corr[c] = exp2f(mrow[cc] - nm);
    mrow[cc] = nm;
    float ds_ = 0.0f;
#pragma unroll
    for (int kx = 0; kx < 16; ++kx) {
      float pv = exp2f(p[c][kx] - nm);
      p[c][kx] = pv;
      ds_ += pv;
    }
    dsum[c] = ds_;
  }
#pragma unroll
  for (int c = 0; c < NC; ++c) dsum[c] += __shfl_xor(dsum[c], 16);
#pragma unroll
  for (int c = 0; c < NC; ++c) dsum[c] += __shfl_xor(dsum[c], 32);
#pragma unroll
  for (int c = 0; c < NC; ++c) {
    int cc = (NC == 2) ? c : 1;
    dden[cc] = dden[cc] * corr[c] + dsum[c];
  }

  // rescale acc + write P to swizzled per-wave LDS
#pragma unroll
  for (int c = 0; c < NC; ++c) {
    int cc = (NC == 2) ? c : 1;
#pragma unroll
    for (int r = 0; r < 4; ++r) {
      float cr = __shfl(corr[c], g * 4 + r);
#pragma unroll
      for (int jf = 0; jf < 4; ++jf) acc[cc][jf][r] *= cr;
    }
    int prow = cc * 16 + lr;
#pragma unroll
    for (int i = 0; i < 4; ++i) {
      uint2 pk;
      pk.x = pack2(p[c][i * 4 + 0], p[c][i * 4 + 1]);
      pk.y = pack2(p[c][i * 4 + 2], p[c][i * 4 + 3]);
      int seg = (i * 2 + (g >> 1)) ^ (prow & 7);
      *(uint2*)(pw + prow * 64 + seg * 8 + (g & 1) * 4) = pk;
    }
  }

  // PV: out[q, dh] += P[q, key] * V^T[dh, key]
#pragma unroll
  for (int c = 0; c < NC; ++c) {
    int cc = (NC == 2) ? c : 1;
    int prow = cc * 16 + lr;
#pragma unroll
    for (int kk = 0; kk < 2; ++kk) {
      bf16x8 pa = *(const bf16x8*)(pw + prow * 64 + (((kk * 4 + g) ^ (prow & 7)) << 3));
#pragma unroll
      for (int jf = 0; jf < 4; ++jf)
        acc[cc][jf] = mma16(pa, vb[kk][jf], acc[cc][jf]);
    }
  }
}

__global__ __launch_bounds__(256, 2) void k_attn(const short* __restrict__ q_b,
                                                 const short* __restrict__ k_b,
                                                 const short* __restrict__ vT_b,
                                                 short* __restrict__ o_b) {
  __shared__ short Ks[3][64 * 64];   // 24 KB
  __shared__ short VTs[3][64 * 64];  // 24 KB
  __shared__ short Ps[4][32 * 64];   // 16 KB
  int tid = threadIdx.x;
  int w = tid >> 6, l = tid & 63;
  int lr = l & 15, g = l >> 4;
  int ib = blockIdx.x, bh = blockIdx.y;
  int qlo = ib, qhi = 31 - ib;
  int qb0 = qlo * 64 + w * 16;  // wave q base, c=0
  int qb1 = qhi * 64 + w * 16;  // wave q base, c=1

  // Q fragments (B-operand: n-row = q = qb_c + lr, k-elems = kk*32 + g*8)
  bf16x8 qf[2][2];
  const short* Qg = q_b + (size_t)bh * 2048 * 64;
#pragma unroll
  for (int kk = 0; kk < 2; ++kk) {
    qf[0][kk] = *(const bf16x8*)(Qg + (size_t)(qb0 + lr) * 64 + kk * 32 + g * 8);
    qf[1][kk] = *(const bf16x8*)(Qg + (size_t)(qb1 + lr) * 64 + kk * 32 + g * 8);
  }

  f32x4 acc[2][4] = {};
  float mrow[2] = {-INFINITY, -INFINITY};
  float dden[2] = {0.0f, 0.0f};
  int nt = qhi + 1;  // >= 17
  const short* Kg = k_b + (size_t)bh * 2048 * 64;
  const short* Vg = vT_b + (size_t)bh * 64 * 2048;
  short* pw = &Ps[w][0];

  // prologue: stage tiles 0 and 1 (4 loads/thread each)
  stage_swz<64>(Kg, 64, &Ks[0][0], tid);
  stage_swz<64>(Vg, 2048, &VTs[0][0], tid);
  stage_swz<64>(Kg + 64 * 64, 64, &Ks[1][0], tid);
  stage_swz<64>(Vg + 64, 2048, &VTs[1][0], tid);

  // Phase A: kt in [0, qlo] -> both c-groups
#pragma unroll 1
  for (int kt = 0; kt <= qlo; ++kt) {
    VMCNT(4);  // wait tile kt's 4 loads; tile kt+1's stay in flight
    BARF();
    if (kt + 2 < nt) {
      int sl = (kt + 2) % 3;
      stage_swz<64>(Kg + (size_t)(kt + 2) * 64 * 64, 64, &Ks[sl][0], tid);
      stage_swz<64>(Vg + (kt + 2) * 64, 2048, &VTs[sl][0], tid);
    }
    int s = kt % 3;
    attn_tile<2>(&Ks[s][0], &VTs[s][0], pw, qf, acc, mrow, dden,
                 kt * 64, qb0, qb1, kt == qlo, false, lr, g);
  }
  // Phase B: kt in (qlo, qhi] -> only c=1
#pragma unroll 1
  for (int kt = qlo + 1; kt < nt; ++kt) {
    VMCNT(4);
    BARF();
    if (kt + 2 < nt) {
      int sl = (kt + 2) % 3;
      stage_swz<64>(Kg + (size_t)(kt + 2) * 64 * 64, 64, &Ks[sl][0], tid);
      stage_swz<64>(Vg + (kt + 2) * 64, 2048, &VTs[sl][0], tid);
    }
    int s = kt % 3;
    attn_tile<1>(&Ks[s][0], &VTs[s][0], pw, qf, acc, mrow, dden,
                 kt * 64, qb0, qb1, false, kt == qhi, lr, g);
  }

  // epilogue: D col = dh-within = lr, row = q-within-16 = g*4 + r
  int hh = bh & 15, b_ = bh >> 4;
#pragma unroll
  for (int c = 0; c < 2; ++c) {
    int qbc = (c == 0) ? qb0 : qb1;
#pragma unroll
    for (int r = 0; r < 4; ++r) {
      float dq = __shfl(dden[c], g * 4 + r);
      float inv = 1.0f / dq;
      int mg = qbc + g * 4 + r;
      size_t rowoff = ((size_t)b_ * 2048 + mg) * 1024 + hh * 64;
#pragma unroll
      for (int jf = 0; jf < 4; ++jf)
        o_b[rowoff + jf * 16 + lr] = f2b(acc[c][jf][r] * inv);
    }
  }
}

// ---------------------------------------------------------------------------
// Launch
// ---------------------------------------------------------------------------
extern "C" void kernel_launch(void* const* d_in, const int* in_sizes, int n_in,
                              void* d_out, int out_size, void* d_ws, size_t ws_size,
                              hipStream_t stream) {
  const float* x     = (const float*)d_in[0];
  const float* wn1   = (const float*)d_in[1];
  const float* wqkv  = (const float*)d_in[2];
  const float* wproj = (const float*)d_in[3];
  const float* wn2   = (const float*)d_in[4];
  const float* wgate = (const float*)d_in[5];
  const float* wup   = (const float*)d_in[6];
  const float* wdown = (const float*)d_in[7];
  float* out = (float*)d_out;
  char* ws = (char*)d_ws;

  short* wqkv_b  = (short*)(ws + 0);         //  6 MB
  short* wproj_b = (short*)(ws + 6291456);   //  2 MB
  short* wgate_b = (short*)(ws + 8388608);   //  8 MB
  short* wup_b   = (short*)(ws + 16777216);  //  8 MB
  short* wdown_b = (short*)(ws + 25165824);  //  8 MB
  short* h_b     = (short*)(ws + 33554432);  //  8 MB (h, then h2)
  short* q_b     = (short*)(ws + 41943040);  //  8 MB
  short* k_b     = (short*)(ws + 50331648);  //  8 MB
  short* vT_b    = (short*)(ws + 58720256);  //  8 MB
  short* ao_b    = (short*)(ws + 67108864);  //  8 MB
  short* act_b   = q_b;   // 32 MB alias over q/k/vT/ao (free after attention)
  float* x1 = out;
  float* kc = out + 4194304;
  float* vc = out + 8388608;

  k_cvt_all<<<16384, 256, 0, stream>>>(wqkv, wqkv_b, wproj, wproj_b,
                                       wgate, wgate_b, wup, wup_b, wdown, wdown_b);

  k_rms<<<4096, 256, 0, stream>>>(x, wn1, h_b);

  // q,k,v = h @ {Wq,Wk,Wv}^T — triple-B fused, grid 256 = 1 block/CU
  k_qkv<<<256, 512, 0, stream>>>(h_b, wqkv_b, q_b, k_b, vT_b, kc, vc);

  k_attn<<<dim3(16, 32), 256, 0, stream>>>(q_b, k_b, vT_b, ao_b);

  // x1 = x + attn @ w_proj^T  (grid 32x16 = 512 blocks)
  k_gemm_skinny<<<512, 256, 0, stream>>>(ao_b, wproj_b, 4096, 1024, 1024, 16,
                                         x, x1);

  k_rms<<<4096, 256, 0, stream>>>(x1, wn2, h_b);

  // act = silu(h2 @ w_gate^T) * (h2 @ w_up^T)  — fused, grid 512, XCD-tiled
  k_mlp<<<512, 512, 0, stream>>>(h_b, wgate_b, wup_b, act_b);

  // x_out = x1 + act @ w_down^T
  k_gemm_skinny<<<512, 256, 0, stream>>>(act_b, wdown_b, 4096, 1024, 4096, 16,
                                         x1, out);
}

// Round 15
// 269.986 us; speedup vs baseline: 1.1805x; 1.0215x over previous
//
#include <hip/hip_runtime.h>
#include <hip/hip_bf16.h>
#include <cstdint>
#include <cstddef>

// B=2, T=2048, D=1024, H=16, DH=64, CTX=2048.  M = B*T = 4096.

using bf16x8 = __attribute__((ext_vector_type(8))) __bf16;
using f32x4  = __attribute__((ext_vector_type(4))) float;

#define VMCNT(n) asm volatile("s_waitcnt vmcnt(" #n ")" ::: "memory")
#define LGKM0()  do { asm volatile("s_waitcnt lgkmcnt(0)" ::: "memory"); \
                      __builtin_amdgcn_sched_barrier(0); } while (0)
#define BARF()   do { asm volatile("" ::: "memory"); __builtin_amdgcn_s_barrier(); \
                      asm volatile("" ::: "memory"); } while (0)

__device__ __forceinline__ short f2b(float f) {
  uint32_t u = __builtin_bit_cast(uint32_t, f);
  uint32_t r = (u + 0x7FFFu + ((u >> 16) & 1u)) >> 16;
  return (short)r;
}
__device__ __forceinline__ float b2f(short s) {
  uint32_t u = ((uint32_t)(uint16_t)s) << 16;
  return __builtin_bit_cast(float, u);
}
// truncation pack of two f32 -> two bf16 in a u32 (P values in [0,1]; bias <0.4%)
__device__ __forceinline__ uint32_t pack2(float a, float b) {
  return (__builtin_bit_cast(uint32_t, a) >> 16) |
         (__builtin_bit_cast(uint32_t, b) & 0xFFFF0000u);
}

__device__ __forceinline__ void gload16(const short* g, short* l) {
  __builtin_amdgcn_global_load_lds(
      (const __attribute__((address_space(1))) void*)g,
      (__attribute__((address_space(3))) void*)l, 16, 0, 0);
}

// ---------------------------------------------------------------------------
// Staging, 64-col (128B) rows, XOR (row&7) swizzle applied on GLOBAL source,
// linear LDS dest (global_load_lds requirement).  Zero-bank-conflict verified.
// ---------------------------------------------------------------------------
template<int ROWS>  // 256 threads, ROWS/32 loads per thread
__device__ __forceinline__ void stage_swz(const short* __restrict__ g, int ldg,
                                          short* lds, int tid) {
#pragma unroll
  for (int jj = 0; jj < ROWS / 32; ++jj) {
    int row = jj * 32 + (tid >> 3);
    int seg = tid & 7;
    gload16(g + (size_t)row * ldg + ((seg ^ (row & 7)) << 3),
            lds + row * 64 + (seg << 3));
  }
}

// 512 threads, one 64-row round per call (1 gload16/thread)
__device__ __forceinline__ void stage_round512(const short* __restrict__ g, int ldg,
                                               short* lds, int tid, int rbase) {
  int row = rbase + (tid >> 3);
  int seg = tid & 7;
  gload16(g + (size_t)row * ldg + ((seg ^ (row & 7)) << 3),
          lds + row * 64 + (seg << 3));
}

__device__ __forceinline__ bf16x8 frag64(const short* lds, int row, int seg) {
  return *(const bf16x8*)(lds + row * 64 + ((seg ^ (row & 7)) << 3));
}

__device__ __forceinline__ f32x4 mma16(bf16x8 a, bf16x8 b, f32x4 c) {
  return __builtin_amdgcn_mfma_f32_16x16x32_bf16(a, b, c, 0, 0, 0);
}

// ---------------------------------------------------------------------------
// Fused weight conversion f32 -> bf16
// ---------------------------------------------------------------------------
__global__ void k_cvt_all(const float* __restrict__ wqkv, short* __restrict__ oqkv,
                          const float* __restrict__ wproj, short* __restrict__ oproj,
                          const float* __restrict__ wgate, short* __restrict__ ogate,
                          const float* __restrict__ wup, short* __restrict__ oup,
                          const float* __restrict__ wdown, short* __restrict__ odown) {
  int bid = blockIdx.x;
  const float* src;
  short* dst;
  int off;
  if (bid < 3072)       { src = wqkv;  dst = oqkv;  off = bid; }
  else if (bid < 4096)  { src = wproj; dst = oproj; off = bid - 3072; }
  else if (bid < 8192)  { src = wgate; dst = ogate; off = bid - 4096; }
  else if (bid < 12288) { src = wup;   dst = oup;   off = bid - 8192; }
  else                  { src = wdown; dst = odown; off = bid - 12288; }
  int i = off * 256 + threadIdx.x;
  float4 v = ((const float4*)src)[i];
  ((short4*)dst)[i] = make_short4(f2b(v.x), f2b(v.y), f2b(v.z), f2b(v.w));
}

// ---------------------------------------------------------------------------
// RMSNorm: one block (256 thr) per row of 1024 f32 -> bf16
// ---------------------------------------------------------------------------
__global__ void k_rms(const float* __restrict__ x, const float* __restrict__ w,
                      short* __restrict__ out) {
  int row = blockIdx.x;
  int tid = threadIdx.x;
  float4 v = *(const float4*)(x + (size_t)row * 1024 + tid * 4);
  float ss = v.x * v.x + v.y * v.y + v.z * v.z + v.w * v.w;
#pragma unroll
  for (int o = 1; o < 64; o <<= 1) ss += __shfl_xor(ss, o);
  __shared__ float sred[4];
  int wid = tid >> 6, lane = tid & 63;
  if (lane == 0) sred[wid] = ss;
  __syncthreads();
  float tot = sred[0] + sred[1] + sred[2] + sred[3];
  float r = rsqrtf(tot * (1.0f / 1024.0f) + 1e-6f);
  float4 wv = *(const float4*)(w + tid * 4);
  short4 o = make_short4(f2b(v.x * r * wv.x), f2b(v.y * r * wv.y),
                         f2b(v.z * r * wv.z), f2b(v.w * r * wv.w));
  *(short4*)(out + (size_t)row * 1024 + tid * 4) = o;
}

// ---------------------------------------------------------------------------
// QKV triple-B kernel: q,k,v = A @ {Wq,Wk,Wv}^T share the A tile.
// BM=128, BN=128 per operand, BK=64, 8 waves.  Grid 256 = 1 block/CU.
// ---------------------------------------------------------------------------
__global__ __launch_bounds__(512) void k_qkv(
    const short* __restrict__ A, const short* __restrict__ W,
    short* __restrict__ q_b, short* __restrict__ k_b, short* __restrict__ vT_b,
    float* __restrict__ kc, float* __restrict__ vc) {
  const int K = 1024, nk = 16;
  __shared__ short As[2][128 * 64];  // 32 KB
  __shared__ short Bq[2][128 * 64];  // 32 KB
  __shared__ short Bk[2][128 * 64];  // 32 KB
  __shared__ short Bv[2][128 * 64];  // 32 KB
  int tid = threadIdx.x;
  int bid = blockIdx.x;
  int swz = (bid & 7) * 32 + (bid >> 3);  // nwg = 256
  int bx = swz & 7, by = swz >> 3;
  int m0 = by * 128, n0 = bx * 128;
  int w = tid >> 6, l = tid & 63;
  int wr = w >> 2, wc = w & 3;
  int lr = l & 15, lseg = l >> 4;
  f32x4 aq[4][2] = {}, ak[4][2] = {}, av[4][2] = {};
  const short* Ab = A + (size_t)m0 * K;
  const short* Qb = W + (size_t)n0 * K;
  const short* Kb = W + (size_t)(1024 + n0) * K;
  const short* Vb = W + (size_t)(2048 + n0) * K;

  // prologue: tile0 all operands (8 loads) + A(1) (2 loads, newest)
  stage_round512(Ab, K, &As[0][0], tid, 0);
  stage_round512(Ab, K, &As[0][0], tid, 64);
  stage_round512(Qb, K, &Bq[0][0], tid, 0);
  stage_round512(Qb, K, &Bq[0][0], tid, 64);
  stage_round512(Kb, K, &Bk[0][0], tid, 0);
  stage_round512(Kb, K, &Bk[0][0], tid, 64);
  stage_round512(Vb, K, &Bv[0][0], tid, 0);
  stage_round512(Vb, K, &Bv[0][0], tid, 64);
  stage_round512(Ab + 64, K, &As[1][0], tid, 0);
  stage_round512(Ab + 64, K, &As[1][0], tid, 64);

  bf16x8 a[4][2], b[2][2];
#pragma unroll 2
  for (int t = 0; t < nk; ++t) {
    short* Sa = &As[t & 1][0];
    short* Sq = &Bq[t & 1][0];
    short* Sk = &Bk[t & 1][0];
    short* Sv = &Bv[t & 1][0];
    short* SqN = &Bq[(t + 1) & 1][0];
    short* SkN = &Bk[(t + 1) & 1][0];
    short* SvN = &Bv[(t + 1) & 1][0];
    const short* Ag2 = Ab + (size_t)(t + 2) * 64;
    const short* Qg1 = Qb + (size_t)(t + 1) * 64;
    const short* Kg1 = Kb + (size_t)(t + 1) * 64;
    const short* Vg1 = Vb + (size_t)(t + 1) * 64;
    bool pf1 = (t + 1 < nk), pf2 = (t + 2 < nk);

    // boundary: tile t resident; keep A(t+2)'s 2 loads in flight
    VMCNT(2);
    BARF();

    // -- P1: q.  reads a(8) + bq(4); stage Bq(t+1), Bk(t+1)
#pragma unroll
    for (int i = 0; i < 4; ++i)
#pragma unroll
      for (int kk = 0; kk < 2; ++kk)
        a[i][kk] = frag64(Sa, wr * 64 + i * 16 + lr, kk * 4 + lseg);
#pragma unroll
    for (int j = 0; j < 2; ++j)
#pragma unroll
      for (int kk = 0; kk < 2; ++kk)
        b[j][kk] = frag64(Sq, wc * 32 + j * 16 + lr, kk * 4 + lseg);
    if (pf1) {
      stage_round512(Qg1, K, SqN, tid, 0);
      stage_round512(Qg1, K, SqN, tid, 64);
      stage_round512(Kg1, K, SkN, tid, 0);
      stage_round512(Kg1, K, SkN, tid, 64);
    }
    BARF();
    LGKM0();
    __builtin_amdgcn_s_setprio(1);
#pragma unroll
    for (int i = 0; i < 4; ++i)
#pragma unroll
      for (int j = 0; j < 2; ++j) {
        aq[i][j] = mma16(a[i][0], b[j][0], aq[i][j]);
        aq[i][j] = mma16(a[i][1], b[j][1], aq[i][j]);
      }
    __builtin_amdgcn_s_setprio(0);

    // -- P2: k.  reads bk(4); stage Bv(t+1)
#pragma unroll
    for (int j = 0; j < 2; ++j)
#pragma unroll
      for (int kk = 0; kk < 2; ++kk)
        b[j][kk] = frag64(Sk, wc * 32 + j * 16 + lr, kk * 4 + lseg);
    if (pf1) {
      stage_round512(Vg1, K, SvN, tid, 0);
      stage_round512(Vg1, K, SvN, tid, 64);
    }
    BARF();
    LGKM0();
    __builtin_amdgcn_s_setprio(1);
#pragma unroll
    for (int i = 0; i < 4; ++i)
#pragma unroll
      for (int j = 0; j < 2; ++j) {
        ak[i][j] = mma16(a[i][0], b[j][0], ak[i][j]);
        ak[i][j] = mma16(a[i][1], b[j][1], ak[i][j]);
      }
    __builtin_amdgcn_s_setprio(0);

    // -- P3: v.  reads bv(4); stage A(t+2) -> Sa (a-reads done since BARF2)
#pragma unroll
    for (int j = 0; j < 2; ++j)
#pragma unroll
      for (int kk = 0; kk < 2; ++kk)
        b[j][kk] = frag64(Sv, wc * 32 + j * 16 + lr, kk * 4 + lseg);
    if (pf2) {
      stage_round512(Ag2, K, Sa, tid, 0);
      stage_round512(Ag2, K, Sa, tid, 64);
    }
    BARF();
    LGKM0();
    __builtin_amdgcn_s_setprio(1);
#pragma unroll
    for (int i = 0; i < 4; ++i)
#pragma unroll
      for (int j = 0; j < 2; ++j) {
        av[i][j] = mma16(a[i][0], b[j][0], av[i][j]);
        av[i][j] = mma16(a[i][1], b[j][1], av[i][j]);
      }
    __builtin_amdgcn_s_setprio(0);
  }

  // epilogue: frag col = lr (n), row = lseg*4 + r (m)
#pragma unroll
  for (int i = 0; i < 4; ++i) {
#pragma unroll
    for (int j = 0; j < 2; ++j) {
#pragma unroll
      for (int r = 0; r < 4; ++r) {
        int m = m0 + wr * 64 + i * 16 + lseg * 4 + r;
        int n = n0 + wc * 32 + j * 16 + lr;
        int hh = n >> 6, dh = n & 63;
        int b_ = m >> 11, tt = m & 2047;
        int bh = b_ * 16 + hh;
        size_t idx = ((size_t)bh * 2048 + tt) * 64 + dh;
        q_b[idx] = f2b(aq[i][j][r]);
        float fk = ak[i][j][r];
        k_b[idx] = f2b(fk);
        kc[idx] = fk;
        float fv = av[i][j][r];
        vT_b[((size_t)bh * 64 + dh) * 2048 + tt] = f2b(fv);
        vc[idx] = fv;
      }
    }
  }
}

// ---------------------------------------------------------------------------
// Fused MLP gate+up: act = silu(A@Wg^T) * (A@Wu^T).  XCD-partitioned grid.
// Tile 256(M) x 128(N), BK=64, 8 waves; 4 phases/K-tile; vmcnt(4) boundary.
// ---------------------------------------------------------------------------
__global__ __launch_bounds__(512) void k_mlp(
    const short* __restrict__ A, const short* __restrict__ Wg,
    const short* __restrict__ Wu, short* __restrict__ outb) {
  const int K = 1024, N = 4096, nk = 16;
  __shared__ short As[2][256 * 64];  // 64 KB
  __shared__ short Bg[2][128 * 64];  // 32 KB
  __shared__ short Bu[2][128 * 64];  // 32 KB
  int tid = threadIdx.x;
  int bid = blockIdx.x;
  // XCD-local partition (grid 512, 64 blocks/XCD): bx = xcd*4 + (idx&3)
  int xcd = bid & 7, idx = bid >> 3;
  int bx = xcd * 4 + (idx & 3);
  int by = idx >> 2;
  int m0 = by * 256, n0 = bx * 128;
  int w = tid >> 6, l = tid & 63;
  int wr = w >> 2, wc = w & 3;
  int lr = l & 15, lseg = l >> 4;
  f32x4 aG[2][4][2] = {}, aU[2][4][2] = {};  // [qm][i][j]
  const short* Ab = A + (size_t)m0 * K;
  const short* Gb = Wg + (size_t)n0 * K;
  const short* Ub = Wu + (size_t)n0 * K;

  // prologue: A(0)x4, Bg(0)x2, Bu(0)x2, A(1)x4  (A(1) newest for vmcnt(4))
  stage_round512(Ab, K, &As[0][0], tid, 0);
  stage_round512(Ab, K, &As[0][0], tid, 64);
  stage_round512(Ab, K, &As[0][0], tid, 128);
  stage_round512(Ab, K, &As[0][0], tid, 192);
  stage_round512(Gb, K, &Bg[0][0], tid, 0);
  stage_round512(Gb, K, &Bg[0][0], tid, 64);
  stage_round512(Ub, K, &Bu[0][0], tid, 0);
  stage_round512(Ub, K, &Bu[0][0], tid, 64);
  stage_round512(Ab + 64, K, &As[1][0], tid, 0);
  stage_round512(Ab + 64, K, &As[1][0], tid, 64);
  stage_round512(Ab + 64, K, &As[1][0], tid, 128);
  stage_round512(Ab + 64, K, &As[1][0], tid, 192);

  bf16x8 a0[4][2], a1[4][2], bg[2][2], bu[2][2];
#pragma unroll 2
  for (int t = 0; t < nk; ++t) {
    short* Sa  = &As[t & 1][0];
    short* Sg  = &Bg[t & 1][0];
    short* Su  = &Bu[t & 1][0];
    short* SgN = &Bg[(t + 1) & 1][0];
    short* SuN = &Bu[(t + 1) & 1][0];
    const short* Ag2 = Ab + (size_t)(t + 2) * 64;
    const short* Gg1 = Gb + (size_t)(t + 1) * 64;
    const short* Ug1 = Ub + (size_t)(t + 1) * 64;
    bool pf1 = (t + 1 < nk), pf2 = (t + 2 < nk);

    // boundary: tile t resident; keep A(t+1)x4 in flight
    VMCNT(4);
    BARF();

    // -- P1: gate.qm0
#pragma unroll
    for (int i = 0; i < 4; ++i)
#pragma unroll
      for (int kk = 0; kk < 2; ++kk)
        a0[i][kk] = frag64(Sa, wr * 128 + i * 16 + lr, kk * 4 + lseg);
#pragma unroll
    for (int j = 0; j < 2; ++j)
#pragma unroll
      for (int kk = 0; kk < 2; ++kk)
        bg[j][kk] = frag64(Sg, wc * 32 + j * 16 + lr, kk * 4 + lseg);
    if (pf1) {
      stage_round512(Gg1, K, SgN, tid, 0);
      stage_round512(Gg1, K, SgN, tid, 64);
      stage_round512(Ug1, K, SuN, tid, 0);
      stage_round512(Ug1, K, SuN, tid, 64);
    }
    BARF();
    LGKM0();
    __builtin_amdgcn_s_setprio(1);
#pragma unroll
    for (int i = 0; i < 4; ++i)
#pragma unroll
      for (int j = 0; j < 2; ++j) {
        aG[0][i][j] = mma16(a0[i][0], bg[j][0], aG[0][i][j]);
        aG[0][i][j] = mma16(a0[i][1], bg[j][1], aG[0][i][j]);
      }
    __builtin_amdgcn_s_setprio(0);

    // -- P2: up.qm0 (reuse a0)
#pragma unroll
    for (int j = 0; j < 2; ++j)
#pragma unroll
      for (int kk = 0; kk < 2; ++kk)
        bu[j][kk] = frag64(Su, wc * 32 + j * 16 + lr, kk * 4 + lseg);
    if (pf2) {
      stage_round512(Ag2, K, Sa, tid, 0);
      stage_round512(Ag2, K, Sa, tid, 128);
    }
    BARF();
    LGKM0();
    __builtin_amdgcn_s_setprio(1);
#pragma unroll
    for (int i = 0; i < 4; ++i)
#pragma unroll
      for (int j = 0; j < 2; ++j) {
        aU[0][i][j] = mma16(a0[i][0], bu[j][0], aU[0][i][j]);
        aU[0][i][j] = mma16(a0[i][1], bu[j][1], aU[0][i][j]);
      }
    __builtin_amdgcn_s_setprio(0);

    // -- P3: gate.qm1 (reuse bg)
#pragma unroll
    for (int i = 0; i < 4; ++i)
#pragma unroll
      for (int kk = 0; kk < 2; ++kk)
        a1[i][kk] = frag64(Sa, wr * 128 + 64 + i * 16 + lr, kk * 4 + lseg);
    BARF();
    LGKM0();
    __builtin_amdgcn_s_setprio(1);
#pragma unroll
    for (int i = 0; i < 4; ++i)
#pragma unroll
      for (int j = 0; j < 2; ++j) {
        aG[1][i][j] = mma16(a1[i][0], bg[j][0], aG[1][i][j]);
        aG[1][i][j] = mma16(a1[i][1], bg[j][1], aG[1][i][j]);
      }
    __builtin_amdgcn_s_setprio(0);

    // -- P4: up.qm1 (reuse a1, bu); stage A(t+2) r1,r3 (rows read at P3)
    if (pf2) {
      stage_round512(Ag2, K, Sa, tid, 64);
      stage_round512(Ag2, K, Sa, tid, 192);
    }
    BARF();
    __builtin_amdgcn_s_setprio(1);
#pragma unroll
    for (int i = 0; i < 4; ++i)
#pragma unroll
      for (int j = 0; j < 2; ++j) {
        aU[1][i][j] = mma16(a1[i][0], bu[j][0], aU[1][i][j]);
        aU[1][i][j] = mma16(a1[i][1], bu[j][1], aU[1][i][j]);
      }
    __builtin_amdgcn_s_setprio(0);
  }

  // epilogue: act = silu(g) * u, bf16
#pragma unroll
  for (int qm = 0; qm < 2; ++qm) {
#pragma unroll
    for (int i = 0; i < 4; ++i) {
#pragma unroll
      for (int j = 0; j < 2; ++j) {
#pragma unroll
        for (int r = 0; r < 4; ++r) {
          int m = m0 + wr * 128 + qm * 64 + i * 16 + lseg * 4 + r;
          int n = n0 + wc * 32 + j * 16 + lr;
          float g = aG[qm][i][j][r];
          float u = aU[qm][i][j][r];
          float s = g / (1.0f + __expf(-g));
          outb[(size_t)m * N + n] = f2b(s * u);
        }
      }
    }
  }
}

// ---------------------------------------------------------------------------
// Split-K down-proj: pc_ks[m,n] = bf16( act[m, ksl] @ wdown[n, ksl]^T ),
// ksl = [ks*2048, (ks+1)*2048).  Tile 256(M) x 128(N), BK=64, 8 waves
// (2M x 4N, wave 128x32), 2 phases of 16 MFMA per K-tile, k_mlp-style
// distributed staging, uniform boundary vmcnt(4).
// Grid 256 = 16(by) x 8(bx=xcd: B slice 1 MB L2-resident) x 2(ks).
// Stage plan: P1(t) stages A(t+1) rounds r1,r3 (rows read at P2(t-1));
//             P2(t) stages A(t+2) r0,r2 + B(t+2) (rows read at P1(t)).
// ---------------------------------------------------------------------------
__global__ __launch_bounds__(512) void k_down(
    const short* __restrict__ A, const short* __restrict__ Bw,
    short* __restrict__ pc0, short* __restrict__ pc1) {
  const int K = 4096, nk = 32;  // 32 K-tiles per half
  __shared__ short As[2][256 * 64];  // 64 KB
  __shared__ short Bs[2][128 * 64];  // 32 KB
  int tid = threadIdx.x;
  int bid = blockIdx.x;
  int xcd = bid & 7, idx = bid >> 3;
  int ks = idx & 1;
  int by = idx >> 1;          // 0..15
  int bx = xcd;               // 0..7
  int m0 = by * 256, n0 = bx * 128;
  int w = tid >> 6, l = tid & 63;
  int wr = w >> 2, wc = w & 3;
  int lr = l & 15, lseg = l >> 4;
  f32x4 acc[2][4][2] = {};  // [qm][i][j]
  const short* Ab = A + (size_t)m0 * K + ks * 2048;
  const short* Bb = Bw + (size_t)n0 * K + ks * 2048;
  short* pc = ks ? pc1 : pc0;

  // prologue: A(0)x4, B(0)x2, then A(1) r0,r2 + B(1)x2 (newest 4)
  stage_round512(Ab, K, &As[0][0], tid, 0);
  stage_round512(Ab, K, &As[0][0], tid, 64);
  stage_round512(Ab, K, &As[0][0], tid, 128);
  stage_round512(Ab, K, &As[0][0], tid, 192);
  stage_round512(Bb, K, &Bs[0][0], tid, 0);
  stage_round512(Bb, K, &Bs[0][0], tid, 64);
  stage_round512(Ab + 64, K, &As[1][0], tid, 0);
  stage_round512(Ab + 64, K, &As[1][0], tid, 128);
  stage_round512(Bb + 64, K, &Bs[1][0], tid, 0);
  stage_round512(Bb + 64, K, &Bs[1][0], tid, 64);

  bf16x8 a0[4][2], a1[4][2], b[2][2];
#pragma unroll 2
  for (int t = 0; t < nk; ++t) {
    int s = t & 1;
    short* Sa = &As[s][0];
    short* Sb = &Bs[s][0];
    short* SaN = &As[s ^ 1][0];
    const short* Ag1 = Ab + (size_t)(t + 1) * 64;
    const short* Ag2 = Ab + (size_t)(t + 2) * 64;
    const short* Bg2 = Bb + (size_t)(t + 2) * 64;
    bool pf1 = (t + 1 < nk), pf2 = (t + 2 < nk);

    // boundary: tile t resident (its 6 loads are oldest); keep 4 in flight
    VMCNT(4);
    BARF();

    // -- P1: reads a0 (rounds r0,r2) + b (all B rows); 16 MFMA qm0.
    //        stage A(t+1) r1,r3 -> other slot (rows read at P2(t-1)).
#pragma unroll
    for (int i = 0; i < 4; ++i)
#pragma unroll
      for (int kk = 0; kk < 2; ++kk)
        a0[i][kk] = frag64(Sa, wr * 128 + i * 16 + lr, kk * 4 + lseg);
#pragma unroll
    for (int j = 0; j < 2; ++j)
#pragma unroll
      for (int kk = 0; kk < 2; ++kk)
        b[j][kk] = frag64(Sb, wc * 32 + j * 16 + lr, kk * 4 + lseg);
    if (pf1) {
      stage_round512(Ag1, K, SaN, tid, 64);
      stage_round512(Ag1, K, SaN, tid, 192);
    }
    BARF();
    LGKM0();
    __builtin_amdgcn_s_setprio(1);
#pragma unroll
    for (int i = 0; i < 4; ++i)
#pragma unroll
      for (int j = 0; j < 2; ++j) {
        acc[0][i][j] = mma16(a0[i][0], b[j][0], acc[0][i][j]);
        acc[0][i][j] = mma16(a0[i][1], b[j][1], acc[0][i][j]);
      }
    __builtin_amdgcn_s_setprio(0);

    // -- P2: reads a1 (rounds r1,r3); 16 MFMA qm1.
    //        stage A(t+2) r0,r2 + B(t+2) -> current slot (rows read at P1).
#pragma unroll
    for (int i = 0; i < 4; ++i)
#pragma unroll
      for (int kk = 0; kk < 2; ++kk)
        a1[i][kk] = frag64(Sa, wr * 128 + 64 + i * 16 + lr, kk * 4 + lseg);
    BARF();
    if (pf2) {
      stage_round512(Ag2, K, Sa, tid, 0);
      stage_round512(Ag2, K, Sa, tid, 128);
      stage_round512(Bg2, K, Sb, tid, 0);
      stage_round512(Bg2, K, Sb, tid, 64);
    }
    LGKM0();
    __builtin_amdgcn_s_setprio(1);
#pragma unroll
    for (int i = 0; i < 4; ++i)
#pragma unroll
      for (int j = 0; j < 2; ++j) {
        acc[1][i][j] = mma16(a1[i][0], b[j][0], acc[1][i][j]);
        acc[1][i][j] = mma16(a1[i][1], b[j][1], acc[1][i][j]);
      }
    __builtin_amdgcn_s_setprio(0);
  }

  // epilogue: bf16 partial, coalesced (n fast in lr)
#pragma unroll
  for (int qm = 0; qm < 2; ++qm) {
#pragma unroll
    for (int i = 0; i < 4; ++i) {
#pragma unroll
      for (int j = 0; j < 2; ++j) {
#pragma unroll
        for (int r = 0; r < 4; ++r) {
          int m = m0 + wr * 128 + qm * 64 + i * 16 + lseg * 4 + r;
          int n = n0 + wc * 32 + j * 16 + lr;
          pc[(size_t)m * 1024 + n] = f2b(acc[qm][i][j][r]);
        }
      }
    }
  }
}

// out = x1 + pc0 + pc1  (in-place on d_out[0:4M), float4 x bf16x4)
__global__ void k_fin(float* __restrict__ out, const short* __restrict__ pc0,
                      const short* __restrict__ pc1) {
  int i = blockIdx.x * 256 + threadIdx.x;  // 1M float4 groups
  float4 v = ((const float4*)out)[i];
  short4 p0 = ((const short4*)pc0)[i];
  short4 p1 = ((const short4*)pc1)[i];
  v.x += b2f(p0.x) + b2f(p1.x);
  v.y += b2f(p0.y) + b2f(p1.y);
  v.z += b2f(p0.z) + b2f(p1.z);
  v.w += b2f(p0.w) + b2f(p1.w);
  ((float4*)out)[i] = v;
}

// ---------------------------------------------------------------------------
// Skinny GEMM (proj): 128x64 tile, BK=64, ring-3, 4 waves (2M x 2N).
// outf[m,n] = C + res[m,n]   (grid 512, 2 blk/CU)
// ---------------------------------------------------------------------------
__global__ __launch_bounds__(256, 2) void k_gemm_skinny(
    const short* __restrict__ A, const short* __restrict__ Bw,
    int M, int N, int K, int gx,
    const float* __restrict__ res, float* __restrict__ outf) {
  __shared__ short As[3][128 * 64];  // 48 KB
  __shared__ short Bs[3][64 * 64];   // 24 KB
  int tid = threadIdx.x;
  int nwg = gridDim.x, bid = blockIdx.x;
  int swz = (bid & 7) * (nwg >> 3) + (bid >> 3);
  int bx = swz % gx, by = swz / gx;
  int m0 = by * 128, n0 = bx * 64;
  int w = tid >> 6, l = tid & 63;
  int wr = w >> 1, wc = w & 1;
  int lr = l & 15, lseg = l >> 4;
  f32x4 acc[4][2] = {};
  int nk = K >> 6;
  const short* Ab = A + (size_t)m0 * K;
  const short* Bb = Bw + (size_t)n0 * K;

  stage_swz<128>(Ab, K, &As[0][0], tid);
  stage_swz<64>(Bb, K, &Bs[0][0], tid);
  stage_swz<128>(Ab + 64, K, &As[1][0], tid);
  stage_swz<64>(Bb + 64, K, &Bs[1][0], tid);

#pragma unroll 1
  for (int u = 0; u < nk; ++u) {
    VMCNT(6);   // tiles u+1, u+2 may stay in flight (6 loads/tile)
    BARF();
    if (u + 2 < nk) {
      int sl = (u + 2) % 3;
      stage_swz<128>(Ab + (u + 2) * 64, K, &As[sl][0], tid);
      stage_swz<64>(Bb + (u + 2) * 64, K, &Bs[sl][0], tid);
    }
    const short* Asl = &As[u % 3][0];
    const short* Bsl = &Bs[u % 3][0];
    bf16x8 ar[4][2], br[2][2];
#pragma unroll
    for (int i = 0; i < 4; ++i)
#pragma unroll
      for (int kk = 0; kk < 2; ++kk)
        ar[i][kk] = frag64(Asl, wr * 64 + i * 16 + lr, kk * 4 + lseg);
#pragma unroll
    for (int j = 0; j < 2; ++j)
#pragma unroll
      for (int kk = 0; kk < 2; ++kk)
        br[j][kk] = frag64(Bsl, wc * 32 + j * 16 + lr, kk * 4 + lseg);
    LGKM0();
    __builtin_amdgcn_s_setprio(1);
#pragma unroll
    for (int i = 0; i < 4; ++i)
#pragma unroll
      for (int j = 0; j < 2; ++j) {
        acc[i][j] = mma16(ar[i][0], br[j][0], acc[i][j]);
        acc[i][j] = mma16(ar[i][1], br[j][1], acc[i][j]);
      }
    __builtin_amdgcn_s_setprio(0);
  }

#pragma unroll
  for (int i = 0; i < 4; ++i) {
#pragma unroll
    for (int j = 0; j < 2; ++j) {
#pragma unroll
      for (int r = 0; r < 4; ++r) {
        int m = m0 + wr * 64 + i * 16 + (l >> 4) * 4 + r;
        int n = n0 + wc * 32 + j * 16 + lr;
        outf[(size_t)m * N + n] = acc[i][j][r] + res[(size_t)m * N + n];
      }
    }
  }
}

// ---------------------------------------------------------------------------
// Causal flash attention v4 — balanced pairing + ring-3 counted-vmcnt
// prefetch + interleaved c-groups via phase-split loops.
// ---------------------------------------------------------------------------
template<int NC>
__device__ __forceinline__ void attn_tile(
    const short* __restrict__ Ksl, const short* __restrict__ Vsl,
    short* __restrict__ pw,
    const bf16x8 (&qf)[2][2], f32x4 (&acc)[2][4],
    float (&mrow)[2], float (&dden)[2],
    int kv0, int qb0, int qb1, bool band0, bool band1,
    int lr, int g) {
  // hoisted K and V fragments (shared across c-groups)
  bf16x8 kf[4][2], vb[2][4];
#pragma unroll
  for (int i = 0; i < 4; ++i)
#pragma unroll
    for (int kk = 0; kk < 2; ++kk)
      kf[i][kk] = frag64(Ksl, i * 16 + lr, kk * 4 + g);
#pragma unroll
  for (int kk = 0; kk < 2; ++kk)
#pragma unroll
    for (int jf = 0; jf < 4; ++jf)
      vb[kk][jf] = frag64(Vsl, jf * 16 + lr, kk * 4 + g);

  // QK^T for all active c-groups (independent MFMAs -> ILP)
  f32x4 st[NC][4];
#pragma unroll
  for (int c = 0; c < NC; ++c) {
    int cc = (NC == 2) ? c : 1;
#pragma unroll
    for (int i = 0; i < 4; ++i) {
      f32x4 z = {};
      z = mma16(kf[i][0], qf[cc][0], z);
      z = mma16(kf[i][1], qf[cc][1], z);
      st[c][i] = z;
    }
  }

  // online softmax in exp2 domain, both chains interleaved
  const float SC = 0.125f * 1.44269504f;
  float p[NC][16], pm[NC], corr[NC];
#pragma unroll
  for (int c = 0; c < NC; ++c) {
    int cc = (NC == 2) ? c : 1;
    bool band = (cc == 0) ? band0 : band1;
    int qgc = ((cc == 0) ? qb0 : qb1) + lr;
    float m_ = -INFINITY;
#pragma unroll
    for (int i = 0; i < 4; ++i)
#pragma unroll
      for (int r = 0; r < 4; ++r) {
        float v = st[c][i][r] * SC;
        if (band) {
          int key = kv0 + i * 16 + g * 4 + r;
          if (key > qgc) v = -INFINITY;
        }
        p[c][i * 4 + r] = v;
        m_ = fmaxf(m_, v);
      }
    pm[c] = m_;
  }
#pragma unroll
  for (int c = 0; c < NC; ++c) pm[c] = fmaxf(pm[c], __shfl_xor(pm[c], 16));
#pragma unroll
  for (int c = 0; c < NC; ++c) pm[c] = fmaxf(pm[c], __shfl_xor(pm[c], 32));
  float dsum[NC];
#pragma unroll
  for (int c = 0; c < NC; ++c) {
    int cc = (NC == 2) ? c : 1;
    float nm = fmaxf(mrow[cc], pm[c]);
    corr[c] = exp2f(mrow[cc] - nm);
    mrow[cc] = nm;
    float ds_ = 0.0f;
#pragma unroll
    for (int kx = 0; kx < 16; ++kx) {
      float pv = exp2f(p[c][kx] - nm);
      p[c][kx] = pv;
      ds_ += pv;
    }
    dsum[c] = ds_;
  }
#pragma unroll
  for (int c = 0; c < NC; ++c) dsum[c] += __shfl_xor(dsum[c], 16);
#pragma unroll
  for (int c = 0; c < NC; ++c) dsum[c] += __shfl_xor(dsum[c], 32);
#pragma unroll
  for (int c = 0; c < NC; ++c) {
    int cc = (NC == 2) ? c : 1;
    dden[cc] = dden[cc] * corr[c] + dsum[c];
  }

  // rescale acc + write P to swizzled per-wave LDS
#pragma unroll
  for (int c = 0; c < NC; ++c) {
    int cc = (NC == 2) ? c : 1;
#pragma unroll
    for (int r = 0; r < 4; ++r) {
      float cr = __shfl(corr[c], g * 4 + r);
#pragma unroll
      for (int jf = 0; jf < 4; ++jf) acc[cc][jf][r] *= cr;
    }
    int prow = cc * 16 + lr;
#pragma unroll
    for (int i = 0; i < 4; ++i) {
      uint2 pk;
      pk.x = pack2(p[c][i * 4 + 0], p[c][i * 4 + 1]);
      pk.y = pack2(p[c][i * 4 + 2], p[c][i * 4 + 3]);
      int seg = (i * 2 + (g >> 1)) ^ (prow & 7);
      *(uint2*)(pw + prow * 64 + seg * 8 + (g & 1) * 4) = pk;
    }
  }

  // PV: out[q, dh] += P[q, key] * V^T[dh, key]
#pragma unroll
  for (int c = 0; c < NC; ++c) {
    int cc = (NC == 2) ? c : 1;
    int prow = cc * 16 + lr;
#pragma unroll
    for (int kk = 0; kk < 2; ++kk) {
      bf16x8 pa = *(const bf16x8*)(pw + prow * 64 + (((kk * 4 + g) ^ (prow & 7)) << 3));
#pragma unroll
      for (int jf = 0; jf < 4; ++jf)
        acc[cc][jf] = mma16(pa, vb[kk][jf], acc[cc][jf]);
    }
  }
}

__global__ __launch_bounds__(256, 2) void k_attn(const short* __restrict__ q_b,
                                                 const short* __restrict__ k_b,
                                                 const short* __restrict__ vT_b,
                                                 short* __restrict__ o_b) {
  __shared__ short Ks[3][64 * 64];   // 24 KB
  __shared__ short VTs[3][64 * 64];  // 24 KB
  __shared__ short Ps[4][32 * 64];   // 16 KB
  int tid = threadIdx.x;
  int w = tid >> 6, l = tid & 63;
  int lr = l & 15, g = l >> 4;
  int ib = blockIdx.x, bh = blockIdx.y;
  int qlo = ib, qhi = 31 - ib;
  int qb0 = qlo * 64 + w * 16;  // wave q base, c=0
  int qb1 = qhi * 64 + w * 16;  // wave q base, c=1

  // Q fragments (B-operand: n-row = q = qb_c + lr, k-elems = kk*32 + g*8)
  bf16x8 qf[2][2];
  const short* Qg = q_b + (size_t)bh * 2048 * 64;
#pragma unroll
  for (int kk = 0; kk < 2; ++kk) {
    qf[0][kk] = *(const bf16x8*)(Qg + (size_t)(qb0 + lr) * 64 + kk * 32 + g * 8);
    qf[1][kk] = *(const bf16x8*)(Qg + (size_t)(qb1 + lr) * 64 + kk * 32 + g * 8);
  }

  f32x4 acc[2][4] = {};
  float mrow[2] = {-INFINITY, -INFINITY};
  float dden[2] = {0.0f, 0.0f};
  int nt = qhi + 1;  // >= 17
  const short* Kg = k_b + (size_t)bh * 2048 * 64;
  const short* Vg = vT_b + (size_t)bh * 64 * 2048;
  short* pw = &Ps[w][0];

  // prologue: stage tiles 0 and 1 (4 loads/thread each)
  stage_swz<64>(Kg, 64, &Ks[0][0], tid);
  stage_swz<64>(Vg, 2048, &VTs[0][0], tid);
  stage_swz<64>(Kg + 64 * 64, 64, &Ks[1][0], tid);
  stage_swz<64>(Vg + 64, 2048, &VTs[1][0], tid);

  // Phase A: kt in [0, qlo] -> both c-groups
#pragma unroll 1
  for (int kt = 0; kt <= qlo; ++kt) {
    VMCNT(4);  // wait tile kt's 4 loads; tile kt+1's stay in flight
    BARF();
    if (kt + 2 < nt) {
      int sl = (kt + 2) % 3;
      stage_swz<64>(Kg + (size_t)(kt + 2) * 64 * 64, 64, &Ks[sl][0], tid);
      stage_swz<64>(Vg + (kt + 2) * 64, 2048, &VTs[sl][0], tid);
    }
    int s = kt % 3;
    attn_tile<2>(&Ks[s][0], &VTs[s][0], pw, qf, acc, mrow, dden,
                 kt * 64, qb0, qb1, kt == qlo, false, lr, g);
  }
  // Phase B: kt in (qlo, qhi] -> only c=1
#pragma unroll 1
  for (int kt = qlo + 1; kt < nt; ++kt) {
    VMCNT(4);
    BARF();
    if (kt + 2 < nt) {
      int sl = (kt + 2) % 3;
      stage_swz<64>(Kg + (size_t)(kt + 2) * 64 * 64, 64, &Ks[sl][0], tid);
      stage_swz<64>(Vg + (kt + 2) * 64, 2048, &VTs[sl][0], tid);
    }
    int s = kt % 3;
    attn_tile<1>(&Ks[s][0], &VTs[s][0], pw, qf, acc, mrow, dden,
                 kt * 64, qb0, qb1, false, kt == qhi, lr, g);
  }

  // epilogue: D col = dh-within = lr, row = q-within-16 = g*4 + r
  int hh = bh & 15, b_ = bh >> 4;
#pragma unroll
  for (int c = 0; c < 2; ++c) {
    int qbc = (c == 0) ? qb0 : qb1;
#pragma unroll
    for (int r = 0; r < 4; ++r) {
      float dq = __shfl(dden[c], g * 4 + r);
      float inv = 1.0f / dq;
      int mg = qbc + g * 4 + r;
      size_t rowoff = ((size_t)b_ * 2048 + mg) * 1024 + hh * 64;
#pragma unroll
      for (int jf = 0; jf < 4; ++jf)
        o_b[rowoff + jf * 16 + lr] = f2b(acc[c][jf][r] * inv);
    }
  }
}

// ---------------------------------------------------------------------------
// Launch
// ---------------------------------------------------------------------------
extern "C" void kernel_launch(void* const* d_in, const int* in_sizes, int n_in,
                              void* d_out, int out_size, void* d_ws, size_t ws_size,
                              hipStream_t stream) {
  const float* x     = (const float*)d_in[0];
  const float* wn1   = (const float*)d_in[1];
  const float* wqkv  = (const float*)d_in[2];
  const float* wproj = (const float*)d_in[3];
  const float* wn2   = (const float*)d_in[4];
  const float* wgate = (const float*)d_in[5];
  const float* wup   = (const float*)d_in[6];
  const float* wdown = (const float*)d_in[7];
  float* out = (float*)d_out;
  char* ws = (char*)d_ws;

  short* wqkv_b  = (short*)(ws + 0);         //  6 MB
  short* wproj_b = (short*)(ws + 6291456);   //  2 MB
  short* wgate_b = (short*)(ws + 8388608);   //  8 MB (-> pc0 after k_mlp)
  short* wup_b   = (short*)(ws + 16777216);  //  8 MB (-> pc1 after k_mlp)
  short* wdown_b = (short*)(ws + 25165824);  //  8 MB
  short* h_b     = (short*)(ws + 33554432);  //  8 MB (h, then h2)
  short* q_b     = (short*)(ws + 41943040);  //  8 MB
  short* k_b     = (short*)(ws + 50331648);  //  8 MB
  short* vT_b    = (short*)(ws + 58720256);  //  8 MB
  short* ao_b    = (short*)(ws + 67108864);  //  8 MB
  short* act_b   = q_b;   // 32 MB alias over q/k/vT/ao (free after attention)
  short* pc0     = wgate_b;  // 8 MB bf16 partial (wgate_b dead after k_mlp)
  short* pc1     = wup_b;    // 8 MB bf16 partial (wup_b dead after k_mlp)
  float* x1 = out;
  float* kc = out + 4194304;
  float* vc = out + 8388608;

  k_cvt_all<<<16384, 256, 0, stream>>>(wqkv, wqkv_b, wproj, wproj_b,
                                       wgate, wgate_b, wup, wup_b, wdown, wdown_b);

  k_rms<<<4096, 256, 0, stream>>>(x, wn1, h_b);

  // q,k,v = h @ {Wq,Wk,Wv}^T — triple-B fused, grid 256 = 1 block/CU
  k_qkv<<<256, 512, 0, stream>>>(h_b, wqkv_b, q_b, k_b, vT_b, kc, vc);

  k_attn<<<dim3(16, 32), 256, 0, stream>>>(q_b, k_b, vT_b, ao_b);

  // x1 = x + attn @ w_proj^T  (grid 32x16 = 512 blocks)
  k_gemm_skinny<<<512, 256, 0, stream>>>(ao_b, wproj_b, 4096, 1024, 1024, 16,
                                         x, x1);

  k_rms<<<4096, 256, 0, stream>>>(x1, wn2, h_b);

  // act = silu(h2 @ w_gate^T) * (h2 @ w_up^T)  — fused, grid 512, XCD-tiled
  k_mlp<<<512, 512, 0, stream>>>(h_b, wgate_b, wup_b, act_b);

  // split-K down: pc_ks = act @ wdown^T (K halves), then out = x1 + pc0 + pc1
  k_down<<<256, 512, 0, stream>>>(act_b, wdown_b, pc0, pc1);
  k_fin<<<4096, 256, 0, stream>>>(out, pc0, pc1);
}

// Round 16
// 266.382 us; speedup vs baseline: 1.1965x; 1.0135x over previous
//
#include <hip/hip_runtime.h>
#include <hip/hip_bf16.h>
#include <cstdint>
#include <cstddef>

// B=2, T=2048, D=1024, H=16, DH=64, CTX=2048.  M = B*T = 4096.

using bf16x8 = __attribute__((ext_vector_type(8))) __bf16;
using f32x4  = __attribute__((ext_vector_type(4))) float;

#define VMCNT(n) asm volatile("s_waitcnt vmcnt(" #n ")" ::: "memory")
#define LGKM0()  do { asm volatile("s_waitcnt lgkmcnt(0)" ::: "memory"); \
                      __builtin_amdgcn_sched_barrier(0); } while (0)
#define BARF()   do { asm volatile("" ::: "memory"); __builtin_amdgcn_s_barrier(); \
                      asm volatile("" ::: "memory"); } while (0)

__device__ __forceinline__ short f2b(float f) {
  uint32_t u = __builtin_bit_cast(uint32_t, f);
  uint32_t r = (u + 0x7FFFu + ((u >> 16) & 1u)) >> 16;
  return (short)r;
}
__device__ __forceinline__ float b2f(short s) {
  uint32_t u = ((uint32_t)(uint16_t)s) << 16;
  return __builtin_bit_cast(float, u);
}
// truncation pack of two f32 -> two bf16 in a u32 (P values in [0,1]; bias <0.4%)
__device__ __forceinline__ uint32_t pack2(float a, float b) {
  return (__builtin_bit_cast(uint32_t, a) >> 16) |
         (__builtin_bit_cast(uint32_t, b) & 0xFFFF0000u);
}

__device__ __forceinline__ void gload16(const short* g, short* l) {
  __builtin_amdgcn_global_load_lds(
      (const __attribute__((address_space(1))) void*)g,
      (__attribute__((address_space(3))) void*)l, 16, 0, 0);
}

// ---------------------------------------------------------------------------
// Staging, 64-col (128B) rows, XOR (row&7) swizzle applied on GLOBAL source,
// linear LDS dest (global_load_lds requirement).  Zero-bank-conflict verified.
// ---------------------------------------------------------------------------
template<int ROWS>  // 256 threads, ROWS/32 loads per thread
__device__ __forceinline__ void stage_swz(const short* __restrict__ g, int ldg,
                                          short* lds, int tid) {
#pragma unroll
  for (int jj = 0; jj < ROWS / 32; ++jj) {
    int row = jj * 32 + (tid >> 3);
    int seg = tid & 7;
    gload16(g + (size_t)row * ldg + ((seg ^ (row & 7)) << 3),
            lds + row * 64 + (seg << 3));
  }
}

// 512 threads, one 64-row round per call (1 gload16/thread)
__device__ __forceinline__ void stage_round512(const short* __restrict__ g, int ldg,
                                               short* lds, int tid, int rbase) {
  int row = rbase + (tid >> 3);
  int seg = tid & 7;
  gload16(g + (size_t)row * ldg + ((seg ^ (row & 7)) << 3),
          lds + row * 64 + (seg << 3));
}

__device__ __forceinline__ bf16x8 frag64(const short* lds, int row, int seg) {
  return *(const bf16x8*)(lds + row * 64 + ((seg ^ (row & 7)) << 3));
}

__device__ __forceinline__ f32x4 mma16(bf16x8 a, bf16x8 b, f32x4 c) {
  return __builtin_amdgcn_mfma_f32_16x16x32_bf16(a, b, c, 0, 0, 0);
}

// ---------------------------------------------------------------------------
// Fused weight conversion f32 -> bf16
// ---------------------------------------------------------------------------
__global__ void k_cvt_all(const float* __restrict__ wqkv, short* __restrict__ oqkv,
                          const float* __restrict__ wproj, short* __restrict__ oproj,
                          const float* __restrict__ wgate, short* __restrict__ ogate,
                          const float* __restrict__ wup, short* __restrict__ oup,
                          const float* __restrict__ wdown, short* __restrict__ odown) {
  int bid = blockIdx.x;
  const float* src;
  short* dst;
  int off;
  if (bid < 3072)       { src = wqkv;  dst = oqkv;  off = bid; }
  else if (bid < 4096)  { src = wproj; dst = oproj; off = bid - 3072; }
  else if (bid < 8192)  { src = wgate; dst = ogate; off = bid - 4096; }
  else if (bid < 12288) { src = wup;   dst = oup;   off = bid - 8192; }
  else                  { src = wdown; dst = odown; off = bid - 12288; }
  int i = off * 256 + threadIdx.x;
  float4 v = ((const float4*)src)[i];
  ((short4*)dst)[i] = make_short4(f2b(v.x), f2b(v.y), f2b(v.z), f2b(v.w));
}

// ---------------------------------------------------------------------------
// RMSNorm: one block (256 thr) per row of 1024 f32 -> bf16
// ---------------------------------------------------------------------------
__global__ void k_rms(const float* __restrict__ x, const float* __restrict__ w,
                      short* __restrict__ out) {
  int row = blockIdx.x;
  int tid = threadIdx.x;
  float4 v = *(const float4*)(x + (size_t)row * 1024 + tid * 4);
  float ss = v.x * v.x + v.y * v.y + v.z * v.z + v.w * v.w;
#pragma unroll
  for (int o = 1; o < 64; o <<= 1) ss += __shfl_xor(ss, o);
  __shared__ float sred[4];
  int wid = tid >> 6, lane = tid & 63;
  if (lane == 0) sred[wid] = ss;
  __syncthreads();
  float tot = sred[0] + sred[1] + sred[2] + sred[3];
  float r = rsqrtf(tot * (1.0f / 1024.0f) + 1e-6f);
  float4 wv = *(const float4*)(w + tid * 4);
  short4 o = make_short4(f2b(v.x * r * wv.x), f2b(v.y * r * wv.y),
                         f2b(v.z * r * wv.z), f2b(v.w * r * wv.w));
  *(short4*)(out + (size_t)row * 1024 + tid * 4) = o;
}

// ---------------------------------------------------------------------------
// QKV triple-B kernel: q,k,v = A @ {Wq,Wk,Wv}^T share the A tile.
// BM=128, BN=128 per operand, BK=64, 8 waves.  Grid 256 = 1 block/CU.
// ---------------------------------------------------------------------------
__global__ __launch_bounds__(512) void k_qkv(
    const short* __restrict__ A, const short* __restrict__ W,
    short* __restrict__ q_b, short* __restrict__ k_b, short* __restrict__ vT_b,
    float* __restrict__ kc, float* __restrict__ vc) {
  const int K = 1024, nk = 16;
  __shared__ short As[2][128 * 64];  // 32 KB
  __shared__ short Bq[2][128 * 64];  // 32 KB
  __shared__ short Bk[2][128 * 64];  // 32 KB
  __shared__ short Bv[2][128 * 64];  // 32 KB
  int tid = threadIdx.x;
  int bid = blockIdx.x;
  int swz = (bid & 7) * 32 + (bid >> 3);  // nwg = 256
  int bx = swz & 7, by = swz >> 3;
  int m0 = by * 128, n0 = bx * 128;
  int w = tid >> 6, l = tid & 63;
  int wr = w >> 2, wc = w & 3;
  int lr = l & 15, lseg = l >> 4;
  f32x4 aq[4][2] = {}, ak[4][2] = {}, av[4][2] = {};
  const short* Ab = A + (size_t)m0 * K;
  const short* Qb = W + (size_t)n0 * K;
  const short* Kb = W + (size_t)(1024 + n0) * K;
  const short* Vb = W + (size_t)(2048 + n0) * K;

  // prologue: tile0 all operands (8 loads) + A(1) (2 loads, newest)
  stage_round512(Ab, K, &As[0][0], tid, 0);
  stage_round512(Ab, K, &As[0][0], tid, 64);
  stage_round512(Qb, K, &Bq[0][0], tid, 0);
  stage_round512(Qb, K, &Bq[0][0], tid, 64);
  stage_round512(Kb, K, &Bk[0][0], tid, 0);
  stage_round512(Kb, K, &Bk[0][0], tid, 64);
  stage_round512(Vb, K, &Bv[0][0], tid, 0);
  stage_round512(Vb, K, &Bv[0][0], tid, 64);
  stage_round512(Ab + 64, K, &As[1][0], tid, 0);
  stage_round512(Ab + 64, K, &As[1][0], tid, 64);

  bf16x8 a[4][2], b[2][2];
#pragma unroll 2
  for (int t = 0; t < nk; ++t) {
    short* Sa = &As[t & 1][0];
    short* Sq = &Bq[t & 1][0];
    short* Sk = &Bk[t & 1][0];
    short* Sv = &Bv[t & 1][0];
    short* SqN = &Bq[(t + 1) & 1][0];
    short* SkN = &Bk[(t + 1) & 1][0];
    short* SvN = &Bv[(t + 1) & 1][0];
    const short* Ag2 = Ab + (size_t)(t + 2) * 64;
    const short* Qg1 = Qb + (size_t)(t + 1) * 64;
    const short* Kg1 = Kb + (size_t)(t + 1) * 64;
    const short* Vg1 = Vb + (size_t)(t + 1) * 64;
    bool pf1 = (t + 1 < nk), pf2 = (t + 2 < nk);

    // boundary: tile t resident; keep A(t+2)'s 2 loads in flight
    VMCNT(2);
    BARF();

    // -- P1: q.  reads a(8) + bq(4); stage Bq(t+1), Bk(t+1)
#pragma unroll
    for (int i = 0; i < 4; ++i)
#pragma unroll
      for (int kk = 0; kk < 2; ++kk)
        a[i][kk] = frag64(Sa, wr * 64 + i * 16 + lr, kk * 4 + lseg);
#pragma unroll
    for (int j = 0; j < 2; ++j)
#pragma unroll
      for (int kk = 0; kk < 2; ++kk)
        b[j][kk] = frag64(Sq, wc * 32 + j * 16 + lr, kk * 4 + lseg);
    if (pf1) {
      stage_round512(Qg1, K, SqN, tid, 0);
      stage_round512(Qg1, K, SqN, tid, 64);
      stage_round512(Kg1, K, SkN, tid, 0);
      stage_round512(Kg1, K, SkN, tid, 64);
    }
    BARF();
    LGKM0();
    __builtin_amdgcn_s_setprio(1);
#pragma unroll
    for (int i = 0; i < 4; ++i)
#pragma unroll
      for (int j = 0; j < 2; ++j) {
        aq[i][j] = mma16(a[i][0], b[j][0], aq[i][j]);
        aq[i][j] = mma16(a[i][1], b[j][1], aq[i][j]);
      }
    __builtin_amdgcn_s_setprio(0);

    // -- P2: k.  reads bk(4); stage Bv(t+1)
#pragma unroll
    for (int j = 0; j < 2; ++j)
#pragma unroll
      for (int kk = 0; kk < 2; ++kk)
        b[j][kk] = frag64(Sk, wc * 32 + j * 16 + lr, kk * 4 + lseg);
    if (pf1) {
      stage_round512(Vg1, K, SvN, tid, 0);
      stage_round512(Vg1, K, SvN, tid, 64);
    }
    BARF();
    LGKM0();
    __builtin_amdgcn_s_setprio(1);
#pragma unroll
    for (int i = 0; i < 4; ++i)
#pragma unroll
      for (int j = 0; j < 2; ++j) {
        ak[i][j] = mma16(a[i][0], b[j][0], ak[i][j]);
        ak[i][j] = mma16(a[i][1], b[j][1], ak[i][j]);
      }
    __builtin_amdgcn_s_setprio(0);

    // -- P3: v.  reads bv(4); stage A(t+2) -> Sa (a-reads done since BARF2)
#pragma unroll
    for (int j = 0; j < 2; ++j)
#pragma unroll
      for (int kk = 0; kk < 2; ++kk)
        b[j][kk] = frag64(Sv, wc * 32 + j * 16 + lr, kk * 4 + lseg);
    if (pf2) {
      stage_round512(Ag2, K, Sa, tid, 0);
      stage_round512(Ag2, K, Sa, tid, 64);
    }
    BARF();
    LGKM0();
    __builtin_amdgcn_s_setprio(1);
#pragma unroll
    for (int i = 0; i < 4; ++i)
#pragma unroll
      for (int j = 0; j < 2; ++j) {
        av[i][j] = mma16(a[i][0], b[j][0], av[i][j]);
        av[i][j] = mma16(a[i][1], b[j][1], av[i][j]);
      }
    __builtin_amdgcn_s_setprio(0);
  }

  // epilogue: frag col = lr (n), row = lseg*4 + r (m)
#pragma unroll
  for (int i = 0; i < 4; ++i) {
#pragma unroll
    for (int j = 0; j < 2; ++j) {
#pragma unroll
      for (int r = 0; r < 4; ++r) {
        int m = m0 + wr * 64 + i * 16 + lseg * 4 + r;
        int n = n0 + wc * 32 + j * 16 + lr;
        int hh = n >> 6, dh = n & 63;
        int b_ = m >> 11, tt = m & 2047;
        int bh = b_ * 16 + hh;
        size_t idx = ((size_t)bh * 2048 + tt) * 64 + dh;
        q_b[idx] = f2b(aq[i][j][r]);
        float fk = ak[i][j][r];
        k_b[idx] = f2b(fk);
        kc[idx] = fk;
        float fv = av[i][j][r];
        vT_b[((size_t)bh * 64 + dh) * 2048 + tt] = f2b(fv);
        vc[idx] = fv;
      }
    }
  }
}

// ---------------------------------------------------------------------------
// Fused MLP gate+up v2 — 2-phase schedule: act = silu(A@Wg^T) * (A@Wu^T).
// Tile 256(M) x 128(N), BK=64, 8 waves, XCD-partitioned grid (512).
// Per K-tile: 3 barriers (was 5), 32-MFMA runs (was 16).
//   P1: reads a0(8)+bg(4)+bu(4); stage B(t+1)x4 + A(t+1) r1,r3;
//       32 MFMA (gate.qm0 + up.qm0).
//   P2: reads a1(8); stage A(t+2) r0,r2; 32 MFMA (gate.qm1 + up.qm1).
// Boundary vmcnt(2) keeps exactly A(t+1) r0,r2 (issued P2(t-1)) in flight.
// WAR: B slot rows read only at P1(t-1); A r1,r3 read at P2(t-1);
//      A r0,r2 read at P1(t) — each >= 1 barrier before its staging.
// ---------------------------------------------------------------------------
__global__ __launch_bounds__(512) void k_mlp(
    const short* __restrict__ A, const short* __restrict__ Wg,
    const short* __restrict__ Wu, short* __restrict__ outb) {
  const int K = 1024, N = 4096, nk = 16;
  __shared__ short As[2][256 * 64];  // 64 KB
  __shared__ short Bg[2][128 * 64];  // 32 KB
  __shared__ short Bu[2][128 * 64];  // 32 KB
  int tid = threadIdx.x;
  int bid = blockIdx.x;
  // XCD-local partition (grid 512, 64 blocks/XCD): bx = xcd*4 + (idx&3)
  int xcd = bid & 7, idx = bid >> 3;
  int bx = xcd * 4 + (idx & 3);
  int by = idx >> 2;
  int m0 = by * 256, n0 = bx * 128;
  int w = tid >> 6, l = tid & 63;
  int wr = w >> 2, wc = w & 3;
  int lr = l & 15, lseg = l >> 4;
  f32x4 aG[2][4][2] = {}, aU[2][4][2] = {};  // [qm][i][j]
  const short* Ab = A + (size_t)m0 * K;
  const short* Gb = Wg + (size_t)n0 * K;
  const short* Ub = Wu + (size_t)n0 * K;

  // prologue: A(0)x4, Bg(0)x2, Bu(0)x2, A(1) r0,r2 (newest 2 for vmcnt(2))
  stage_round512(Ab, K, &As[0][0], tid, 0);
  stage_round512(Ab, K, &As[0][0], tid, 64);
  stage_round512(Ab, K, &As[0][0], tid, 128);
  stage_round512(Ab, K, &As[0][0], tid, 192);
  stage_round512(Gb, K, &Bg[0][0], tid, 0);
  stage_round512(Gb, K, &Bg[0][0], tid, 64);
  stage_round512(Ub, K, &Bu[0][0], tid, 0);
  stage_round512(Ub, K, &Bu[0][0], tid, 64);
  stage_round512(Ab + 64, K, &As[1][0], tid, 0);
  stage_round512(Ab + 64, K, &As[1][0], tid, 128);

  bf16x8 a0[4][2], a1[4][2], bg[2][2], bu[2][2];
#pragma unroll 2
  for (int t = 0; t < nk; ++t) {
    int s = t & 1;
    short* Sa  = &As[s][0];
    short* Sg  = &Bg[s][0];
    short* Su  = &Bu[s][0];
    short* SaN = &As[s ^ 1][0];
    short* SgN = &Bg[s ^ 1][0];
    short* SuN = &Bu[s ^ 1][0];
    const short* Ag1 = Ab + (size_t)(t + 1) * 64;
    const short* Ag2 = Ab + (size_t)(t + 2) * 64;
    const short* Gg1 = Gb + (size_t)(t + 1) * 64;
    const short* Ug1 = Ub + (size_t)(t + 1) * 64;
    bool pf1 = (t + 1 < nk), pf2 = (t + 2 < nk);

    // boundary: tile t fully resident; keep A(t+1) r0,r2 in flight
    VMCNT(2);
    BARF();

    // -- P1: reads a0 (rounds r0,r2) + bg + bu;
    //        stage B(t+1)x4 + A(t+1) r1,r3; 32 MFMA (gate.qm0 + up.qm0)
#pragma unroll
    for (int i = 0; i < 4; ++i)
#pragma unroll
      for (int kk = 0; kk < 2; ++kk)
        a0[i][kk] = frag64(Sa, wr * 128 + i * 16 + lr, kk * 4 + lseg);
#pragma unroll
    for (int j = 0; j < 2; ++j)
#pragma unroll
      for (int kk = 0; kk < 2; ++kk) {
        bg[j][kk] = frag64(Sg, wc * 32 + j * 16 + lr, kk * 4 + lseg);
        bu[j][kk] = frag64(Su, wc * 32 + j * 16 + lr, kk * 4 + lseg);
      }
    if (pf1) {
      stage_round512(Gg1, K, SgN, tid, 0);
      stage_round512(Gg1, K, SgN, tid, 64);
      stage_round512(Ug1, K, SuN, tid, 0);
      stage_round512(Ug1, K, SuN, tid, 64);
      stage_round512(Ag1, K, SaN, tid, 64);
      stage_round512(Ag1, K, SaN, tid, 192);
    }
    BARF();
    LGKM0();
    __builtin_amdgcn_s_setprio(1);
#pragma unroll
    for (int i = 0; i < 4; ++i)
#pragma unroll
      for (int j = 0; j < 2; ++j) {
        aG[0][i][j] = mma16(a0[i][0], bg[j][0], aG[0][i][j]);
        aG[0][i][j] = mma16(a0[i][1], bg[j][1], aG[0][i][j]);
        aU[0][i][j] = mma16(a0[i][0], bu[j][0], aU[0][i][j]);
        aU[0][i][j] = mma16(a0[i][1], bu[j][1], aU[0][i][j]);
      }
    __builtin_amdgcn_s_setprio(0);

    // -- P2: reads a1 (rounds r1,r3); stage A(t+2) r0,r2 (read at P1);
    //        32 MFMA (gate.qm1 + up.qm1)
#pragma unroll
    for (int i = 0; i < 4; ++i)
#pragma unroll
      for (int kk = 0; kk < 2; ++kk)
        a1[i][kk] = frag64(Sa, wr * 128 + 64 + i * 16 + lr, kk * 4 + lseg);
    if (pf2) {
      stage_round512(Ag2, K, Sa, tid, 0);
      stage_round512(Ag2, K, Sa, tid, 128);
    }
    BARF();
    LGKM0();
    __builtin_amdgcn_s_setprio(1);
#pragma unroll
    for (int i = 0; i < 4; ++i)
#pragma unroll
      for (int j = 0; j < 2; ++j) {
        aG[1][i][j] = mma16(a1[i][0], bg[j][0], aG[1][i][j]);
        aG[1][i][j] = mma16(a1[i][1], bg[j][1], aG[1][i][j]);
        aU[1][i][j] = mma16(a1[i][0], bu[j][0], aU[1][i][j]);
        aU[1][i][j] = mma16(a1[i][1], bu[j][1], aU[1][i][j]);
      }
    __builtin_amdgcn_s_setprio(0);
  }

  // epilogue: act = silu(g) * u, bf16
#pragma unroll
  for (int qm = 0; qm < 2; ++qm) {
#pragma unroll
    for (int i = 0; i < 4; ++i) {
#pragma unroll
      for (int j = 0; j < 2; ++j) {
#pragma unroll
        for (int r = 0; r < 4; ++r) {
          int m = m0 + wr * 128 + qm * 64 + i * 16 + lseg * 4 + r;
          int n = n0 + wc * 32 + j * 16 + lr;
          float g = aG[qm][i][j][r];
          float u = aU[qm][i][j][r];
          float s = g / (1.0f + __expf(-g));
          outb[(size_t)m * N + n] = f2b(s * u);
        }
      }
    }
  }
}

// ---------------------------------------------------------------------------
// Split-K down-proj: pc_ks[m,n] = bf16( act[m, ksl] @ wdown[n, ksl]^T ).
// Tile 256x128, BK=64, 8 waves, 2 phases of 16+16 MFMA, vmcnt(4) boundary.
// Grid 256 = 16(by) x 8(bx=xcd) x 2(ks).
// ---------------------------------------------------------------------------
__global__ __launch_bounds__(512) void k_down(
    const short* __restrict__ A, const short* __restrict__ Bw,
    short* __restrict__ pc0, short* __restrict__ pc1) {
  const int K = 4096, nk = 32;  // 32 K-tiles per half
  __shared__ short As[2][256 * 64];  // 64 KB
  __shared__ short Bs[2][128 * 64];  // 32 KB
  int tid = threadIdx.x;
  int bid = blockIdx.x;
  int xcd = bid & 7, idx = bid >> 3;
  int ks = idx & 1;
  int by = idx >> 1;          // 0..15
  int bx = xcd;               // 0..7
  int m0 = by * 256, n0 = bx * 128;
  int w = tid >> 6, l = tid & 63;
  int wr = w >> 2, wc = w & 3;
  int lr = l & 15, lseg = l >> 4;
  f32x4 acc[2][4][2] = {};  // [qm][i][j]
  const short* Ab = A + (size_t)m0 * K + ks * 2048;
  const short* Bb = Bw + (size_t)n0 * K + ks * 2048;
  short* pc = ks ? pc1 : pc0;

  // prologue: A(0)x4, B(0)x2, then A(1) r0,r2 + B(1)x2 (newest 4)
  stage_round512(Ab, K, &As[0][0], tid, 0);
  stage_round512(Ab, K, &As[0][0], tid, 64);
  stage_round512(Ab, K, &As[0][0], tid, 128);
  stage_round512(Ab, K, &As[0][0], tid, 192);
  stage_round512(Bb, K, &Bs[0][0], tid, 0);
  stage_round512(Bb, K, &Bs[0][0], tid, 64);
  stage_round512(Ab + 64, K, &As[1][0], tid, 0);
  stage_round512(Ab + 64, K, &As[1][0], tid, 128);
  stage_round512(Bb + 64, K, &Bs[1][0], tid, 0);
  stage_round512(Bb + 64, K, &Bs[1][0], tid, 64);

  bf16x8 a0[4][2], a1[4][2], b[2][2];
#pragma unroll 2
  for (int t = 0; t < nk; ++t) {
    int s = t & 1;
    short* Sa = &As[s][0];
    short* Sb = &Bs[s][0];
    short* SaN = &As[s ^ 1][0];
    const short* Ag1 = Ab + (size_t)(t + 1) * 64;
    const short* Ag2 = Ab + (size_t)(t + 2) * 64;
    const short* Bg2 = Bb + (size_t)(t + 2) * 64;
    bool pf1 = (t + 1 < nk), pf2 = (t + 2 < nk);

    // boundary: tile t resident (its 6 loads are oldest); keep 4 in flight
    VMCNT(4);
    BARF();

    // -- P1: reads a0 (rounds r0,r2) + b (all B rows); 16 MFMA qm0.
    //        stage A(t+1) r1,r3 -> other slot (rows read at P2(t-1)).
#pragma unroll
    for (int i = 0; i < 4; ++i)
#pragma unroll
      for (int kk = 0; kk < 2; ++kk)
        a0[i][kk] = frag64(Sa, wr * 128 + i * 16 + lr, kk * 4 + lseg);
#pragma unroll
    for (int j = 0; j < 2; ++j)
#pragma unroll
      for (int kk = 0; kk < 2; ++kk)
        b[j][kk] = frag64(Sb, wc * 32 + j * 16 + lr, kk * 4 + lseg);
    if (pf1) {
      stage_round512(Ag1, K, SaN, tid, 64);
      stage_round512(Ag1, K, SaN, tid, 192);
    }
    BARF();
    LGKM0();
    __builtin_amdgcn_s_setprio(1);
#pragma unroll
    for (int i = 0; i < 4; ++i)
#pragma unroll
      for (int j = 0; j < 2; ++j) {
        acc[0][i][j] = mma16(a0[i][0], b[j][0], acc[0][i][j]);
        acc[0][i][j] = mma16(a0[i][1], b[j][1], acc[0][i][j]);
      }
    __builtin_amdgcn_s_setprio(0);

    // -- P2: reads a1 (rounds r1,r3); 16 MFMA qm1.
    //        stage A(t+2) r0,r2 + B(t+2) -> current slot (rows read at P1).
#pragma unroll
    for (int i = 0; i < 4; ++i)
#pragma unroll
      for (int kk = 0; kk < 2; ++kk)
        a1[i][kk] = frag64(Sa, wr * 128 + 64 + i * 16 + lr, kk * 4 + lseg);
    BARF();
    if (pf2) {
      stage_round512(Ag2, K, Sa, tid, 0);
      stage_round512(Ag2, K, Sa, tid, 128);
      stage_round512(Bg2, K, Sb, tid, 0);
      stage_round512(Bg2, K, Sb, tid, 64);
    }
    LGKM0();
    __builtin_amdgcn_s_setprio(1);
#pragma unroll
    for (int i = 0; i < 4; ++i)
#pragma unroll
      for (int j = 0; j < 2; ++j) {
        acc[1][i][j] = mma16(a1[i][0], b[j][0], acc[1][i][j]);
        acc[1][i][j] = mma16(a1[i][1], b[j][1], acc[1][i][j]);
      }
    __builtin_amdgcn_s_setprio(0);
  }

  // epilogue: bf16 partial, coalesced (n fast in lr)
#pragma unroll
  for (int qm = 0; qm < 2; ++qm) {
#pragma unroll
    for (int i = 0; i < 4; ++i) {
#pragma unroll
      for (int j = 0; j < 2; ++j) {
#pragma unroll
        for (int r = 0; r < 4; ++r) {
          int m = m0 + wr * 128 + qm * 64 + i * 16 + lseg * 4 + r;
          int n = n0 + wc * 32 + j * 16 + lr;
          pc[(size_t)m * 1024 + n] = f2b(acc[qm][i][j][r]);
        }
      }
    }
  }
}

// out = x1 + pc0 + pc1  (in-place on d_out[0:4M), float4 x bf16x4)
__global__ void k_fin(float* __restrict__ out, const short* __restrict__ pc0,
                      const short* __restrict__ pc1) {
  int i = blockIdx.x * 256 + threadIdx.x;  // 1M float4 groups
  float4 v = ((const float4*)out)[i];
  short4 p0 = ((const short4*)pc0)[i];
  short4 p1 = ((const short4*)pc1)[i];
  v.x += b2f(p0.x) + b2f(p1.x);
  v.y += b2f(p0.y) + b2f(p1.y);
  v.z += b2f(p0.z) + b2f(p1.z);
  v.w += b2f(p0.w) + b2f(p1.w);
  ((float4*)out)[i] = v;
}

// ---------------------------------------------------------------------------
// Skinny GEMM (proj): 128x64 tile, BK=64, ring-3, 4 waves (2M x 2N).
// outf[m,n] = C + res[m,n]   (grid 512, 2 blk/CU)
// ---------------------------------------------------------------------------
__global__ __launch_bounds__(256, 2) void k_gemm_skinny(
    const short* __restrict__ A, const short* __restrict__ Bw,
    int M, int N, int K, int gx,
    const float* __restrict__ res, float* __restrict__ outf) {
  __shared__ short As[3][128 * 64];  // 48 KB
  __shared__ short Bs[3][64 * 64];   // 24 KB
  int tid = threadIdx.x;
  int nwg = gridDim.x, bid = blockIdx.x;
  int swz = (bid & 7) * (nwg >> 3) + (bid >> 3);
  int bx = swz % gx, by = swz / gx;
  int m0 = by * 128, n0 = bx * 64;
  int w = tid >> 6, l = tid & 63;
  int wr = w >> 1, wc = w & 1;
  int lr = l & 15, lseg = l >> 4;
  f32x4 acc[4][2] = {};
  int nk = K >> 6;
  const short* Ab = A + (size_t)m0 * K;
  const short* Bb = Bw + (size_t)n0 * K;

  stage_swz<128>(Ab, K, &As[0][0], tid);
  stage_swz<64>(Bb, K, &Bs[0][0], tid);
  stage_swz<128>(Ab + 64, K, &As[1][0], tid);
  stage_swz<64>(Bb + 64, K, &Bs[1][0], tid);

#pragma unroll 1
  for (int u = 0; u < nk; ++u) {
    VMCNT(6);   // tiles u+1, u+2 may stay in flight (6 loads/tile)
    BARF();
    if (u + 2 < nk) {
      int sl = (u + 2) % 3;
      stage_swz<128>(Ab + (u + 2) * 64, K, &As[sl][0], tid);
      stage_swz<64>(Bb + (u + 2) * 64, K, &Bs[sl][0], tid);
    }
    const short* Asl = &As[u % 3][0];
    const short* Bsl = &Bs[u % 3][0];
    bf16x8 ar[4][2], br[2][2];
#pragma unroll
    for (int i = 0; i < 4; ++i)
#pragma unroll
      for (int kk = 0; kk < 2; ++kk)
        ar[i][kk] = frag64(Asl, wr * 64 + i * 16 + lr, kk * 4 + lseg);
#pragma unroll
    for (int j = 0; j < 2; ++j)
#pragma unroll
      for (int kk = 0; kk < 2; ++kk)
        br[j][kk] = frag64(Bsl, wc * 32 + j * 16 + lr, kk * 4 + lseg);
    LGKM0();
    __builtin_amdgcn_s_setprio(1);
#pragma unroll
    for (int i = 0; i < 4; ++i)
#pragma unroll
      for (int j = 0; j < 2; ++j) {
        acc[i][j] = mma16(ar[i][0], br[j][0], acc[i][j]);
        acc[i][j] = mma16(ar[i][1], br[j][1], acc[i][j]);
      }
    __builtin_amdgcn_s_setprio(0);
  }

#pragma unroll
  for (int i = 0; i < 4; ++i) {
#pragma unroll
    for (int j = 0; j < 2; ++j) {
#pragma unroll
      for (int r = 0; r < 4; ++r) {
        int m = m0 + wr * 64 + i * 16 + (l >> 4) * 4 + r;
        int n = n0 + wc * 32 + j * 16 + lr;
        outf[(size_t)m * N + n] = acc[i][j][r] + res[(size_t)m * N + n];
      }
    }
  }
}

// ---------------------------------------------------------------------------
// Causal flash attention v4 — balanced pairing + ring-3 counted-vmcnt
// prefetch + interleaved c-groups via phase-split loops.
// ---------------------------------------------------------------------------
template<int NC>
__device__ __forceinline__ void attn_tile(
    const short* __restrict__ Ksl, const short* __restrict__ Vsl,
    short* __restrict__ pw,
    const bf16x8 (&qf)[2][2], f32x4 (&acc)[2][4],
    float (&mrow)[2], float (&dden)[2],
    int kv0, int qb0, int qb1, bool band0, bool band1,
    int lr, int g) {
  // hoisted K and V fragments (shared across c-groups)
  bf16x8 kf[4][2], vb[2][4];
#pragma unroll
  for (int i = 0; i < 4; ++i)
#pragma unroll
    for (int kk = 0; kk < 2; ++kk)
      kf[i][kk] = frag64(Ksl, i * 16 + lr, kk * 4 + g);
#pragma unroll
  for (int kk = 0; kk < 2; ++kk)
#pragma unroll
    for (int jf = 0; jf < 4; ++jf)
      vb[kk][jf] = frag64(Vsl, jf * 16 + lr, kk * 4 + g);

  // QK^T for all active c-groups (independent MFMAs -> ILP)
  f32x4 st[NC][4];
#pragma unroll
  for (int c = 0; c < NC; ++c) {
    int cc = (NC == 2) ? c : 1;
#pragma unroll
    for (int i = 0; i < 4; ++i) {
      f32x4 z = {};
      z = mma16(kf[i][0], qf[cc][0], z);
      z = mma16(kf[i][1], qf[cc][1], z);
      st[c][i] = z;
    }
  }

  // online softmax in exp2 domain, both chains interleaved
  const float SC = 0.125f * 1.44269504f;
  float p[NC][16], pm[NC], corr[NC];
#pragma unroll
  for (int c = 0; c < NC; ++c) {
    int cc = (NC == 2) ? c : 1;
    bool band = (cc == 0) ? band0 : band1;
    int qgc = ((cc == 0) ? qb0 : qb1) + lr;
    float m_ = -INFINITY;
#pragma unroll
    for (int i = 0; i < 4; ++i)
#pragma unroll
      for (int r = 0; r < 4; ++r) {
        float v = st[c][i][r] * SC;
        if (band) {
          int key = kv0 + i * 16 + g * 4 + r;
          if (key > qgc) v = -INFINITY;
        }
        p[c][i * 4 + r] = v;
        m_ = fmaxf(m_, v);
      }
    pm[c] = m_;
  }
#pragma unroll
  for (int c = 0; c < NC; ++c) pm[c] = fmaxf(pm[c], __shfl_xor(pm[c], 16));
#pragma unroll
  for (int c = 0; c < NC; ++c) pm[c] = fmaxf(pm[c], __shfl_xor(pm[c], 32));
  float dsum[NC];
#pragma unroll
  for (int c = 0; c < NC; ++c) {
    int cc = (NC == 2) ? c : 1;
    float nm = fmaxf(mrow[cc], pm[c]);
    corr[c] = exp2f(mrow[cc] - nm);
    mrow[cc] = nm;
    float ds_ = 0.0f;
#pragma unroll
    for (int kx = 0; kx < 16; ++kx) {
      float pv = exp2f(p[c][kx] - nm);
      p[c][kx] = pv;
      ds_ += pv;
    }
    dsum[c] = ds_;
  }
#pragma unroll
  for (int c = 0; c < NC; ++c) dsum[c] += __shfl_xor(dsum[c], 16);
#pragma unroll
  for (int c = 0; c < NC; ++c) dsum[c] += __shfl_xor(dsum[c], 32);
#pragma unroll
  for (int c = 0; c < NC; ++c) {
    int cc = (NC == 2) ? c : 1;
    dden[cc] = dden[cc] * corr[c] + dsum[c];
  }

  // rescale acc + write P to swizzled per-wave LDS
#pragma unroll
  for (int c = 0; c < NC; ++c) {
    int cc = (NC == 2) ? c : 1;
#pragma unroll
    for (int r = 0; r < 4; ++r) {
      float cr = __shfl(corr[c], g * 4 + r);
#pragma unroll
      for (int jf = 0; jf < 4; ++jf) acc[cc][jf][r] *= cr;
    }
    int prow = cc * 16 + lr;
#pragma unroll
    for (int i = 0; i < 4; ++i) {
      uint2 pk;
      pk.x = pack2(p[c][i * 4 + 0], p[c][i * 4 + 1]);
      pk.y = pack2(p[c][i * 4 + 2], p[c][i * 4 + 3]);
      int seg = (i * 2 + (g >> 1)) ^ (prow & 7);
      *(uint2*)(pw + prow * 64 + seg * 8 + (g & 1) * 4) = pk;
    }
  }

  // PV: out[q, dh] += P[q, key] * V^T[dh, key]
#pragma unroll
  for (int c = 0; c < NC; ++c) {
    int cc = (NC == 2) ? c : 1;
    int prow = cc * 16 + lr;
#pragma unroll
    for (int kk = 0; kk < 2; ++kk) {
      bf16x8 pa = *(const bf16x8*)(pw + prow * 64 + (((kk * 4 + g) ^ (prow & 7)) << 3));
#pragma unroll
      for (int jf = 0; jf < 4; ++jf)
        acc[cc][jf] = mma16(pa, vb[kk][jf], acc[cc][jf]);
    }
  }
}

__global__ __launch_bounds__(256, 2) void k_attn(const short* __restrict__ q_b,
                                                 const short* __restrict__ k_b,
                                                 const short* __restrict__ vT_b,
                                                 short* __restrict__ o_b) {
  __shared__ short Ks[3][64 * 64];   // 24 KB
  __shared__ short VTs[3][64 * 64];  // 24 KB
  __shared__ short Ps[4][32 * 64];   // 16 KB
  int tid = threadIdx.x;
  int w = tid >> 6, l = tid & 63;
  int lr = l & 15, g = l >> 4;
  int ib = blockIdx.x, bh = blockIdx.y;
  int qlo = ib, qhi = 31 - ib;
  int qb0 = qlo * 64 + w * 16;  // wave q base, c=0
  int qb1 = qhi * 64 + w * 16;  // wave q base, c=1

  // Q fragments (B-operand: n-row = q = qb_c + lr, k-elems = kk*32 + g*8)
  bf16x8 qf[2][2];
  const short* Qg = q_b + (size_t)bh * 2048 * 64;
#pragma unroll
  for (int kk = 0; kk < 2; ++kk) {
    qf[0][kk] = *(const bf16x8*)(Qg + (size_t)(qb0 + lr) * 64 + kk * 32 + g * 8);
    qf[1][kk] = *(const bf16x8*)(Qg + (size_t)(qb1 + lr) * 64 + kk * 32 + g * 8);
  }

  f32x4 acc[2][4] = {};
  float mrow[2] = {-INFINITY, -INFINITY};
  float dden[2] = {0.0f, 0.0f};
  int nt = qhi + 1;  // >= 17
  const short* Kg = k_b + (size_t)bh * 2048 * 64;
  const short* Vg = vT_b + (size_t)bh * 64 * 2048;
  short* pw = &Ps[w][0];

  // prologue: stage tiles 0 and 1 (4 loads/thread each)
  stage_swz<64>(Kg, 64, &Ks[0][0], tid);
  stage_swz<64>(Vg, 2048, &VTs[0][0], tid);
  stage_swz<64>(Kg + 64 * 64, 64, &Ks[1][0], tid);
  stage_swz<64>(Vg + 64, 2048, &VTs[1][0], tid);

  // Phase A: kt in [0, qlo] -> both c-groups
#pragma unroll 1
  for (int kt = 0; kt <= qlo; ++kt) {
    VMCNT(4);  // wait tile kt's 4 loads; tile kt+1's stay in flight
    BARF();
    if (kt + 2 < nt) {
      int sl = (kt + 2) % 3;
      stage_swz<64>(Kg + (size_t)(kt + 2) * 64 * 64, 64, &Ks[sl][0], tid);
      stage_swz<64>(Vg + (kt + 2) * 64, 2048, &VTs[sl][0], tid);
    }
    int s = kt % 3;
    attn_tile<2>(&Ks[s][0], &VTs[s][0], pw, qf, acc, mrow, dden,
                 kt * 64, qb0, qb1, kt == qlo, false, lr, g);
  }
  // Phase B: kt in (qlo, qhi] -> only c=1
#pragma unroll 1
  for (int kt = qlo + 1; kt < nt; ++kt) {
    VMCNT(4);
    BARF();
    if (kt + 2 < nt) {
      int sl = (kt + 2) % 3;
      stage_swz<64>(Kg + (size_t)(kt + 2) * 64 * 64, 64, &Ks[sl][0], tid);
      stage_swz<64>(Vg + (kt + 2) * 64, 2048, &VTs[sl][0], tid);
    }
    int s = kt % 3;
    attn_tile<1>(&Ks[s][0], &VTs[s][0], pw, qf, acc, mrow, dden,
                 kt * 64, qb0, qb1, false, kt == qhi, lr, g);
  }

  // epilogue: D col = dh-within = lr, row = q-within-16 = g*4 + r
  int hh = bh & 15, b_ = bh >> 4;
#pragma unroll
  for (int c = 0; c < 2; ++c) {
    int qbc = (c == 0) ? qb0 : qb1;
#pragma unroll
    for (int r = 0; r < 4; ++r) {
      float dq = __shfl(dden[c], g * 4 + r);
      float inv = 1.0f / dq;
      int mg = qbc + g * 4 + r;
      size_t rowoff = ((size_t)b_ * 2048 + mg) * 1024 + hh * 64;
#pragma unroll
      for (int jf = 0; jf < 4; ++jf)
        o_b[rowoff + jf * 16 + lr] = f2b(acc[c][jf][r] * inv);
    }
  }
}

// ---------------------------------------------------------------------------
// Launch
// ---------------------------------------------------------------------------
extern "C" void kernel_launch(void* const* d_in, const int* in_sizes, int n_in,
                              void* d_out, int out_size, void* d_ws, size_t ws_size,
                              hipStream_t stream) {
  const float* x     = (const float*)d_in[0];
  const float* wn1   = (const float*)d_in[1];
  const float* wqkv  = (const float*)d_in[2];
  const float* wproj = (const float*)d_in[3];
  const float* wn2   = (const float*)d_in[4];
  const float* wgate = (const float*)d_in[5];
  const float* wup   = (const float*)d_in[6];
  const float* wdown = (const float*)d_in[7];
  float* out = (float*)d_out;
  char* ws = (char*)d_ws;

  short* wqkv_b  = (short*)(ws + 0);         //  6 MB
  short* wproj_b = (short*)(ws + 6291456);   //  2 MB
  short* wgate_b = (short*)(ws + 8388608);   //  8 MB (-> pc0 after k_mlp)
  short* wup_b   = (short*)(ws + 16777216);  //  8 MB (-> pc1 after k_mlp)
  short* wdown_b = (short*)(ws + 25165824);  //  8 MB
  short* h_b     = (short*)(ws + 33554432);  //  8 MB (h, then h2)
  short* q_b     = (short*)(ws + 41943040);  //  8 MB
  short* k_b     = (short*)(ws + 50331648);  //  8 MB
  short* vT_b    = (short*)(ws + 58720256);  //  8 MB
  short* ao_b    = (short*)(ws + 67108864);  //  8 MB
  short* act_b   = q_b;   // 32 MB alias over q/k/vT/ao (free after attention)
  short* pc0     = wgate_b;  // 8 MB bf16 partial (wgate_b dead after k_mlp)
  short* pc1     = wup_b;    // 8 MB bf16 partial (wup_b dead after k_mlp)
  float* x1 = out;
  float* kc = out + 4194304;
  float* vc = out + 8388608;

  k_cvt_all<<<16384, 256, 0, stream>>>(wqkv, wqkv_b, wproj, wproj_b,
                                       wgate, wgate_b, wup, wup_b, wdown, wdown_b);

  k_rms<<<4096, 256, 0, stream>>>(x, wn1, h_b);

  // q,k,v = h @ {Wq,Wk,Wv}^T — triple-B fused, grid 256 = 1 block/CU
  k_qkv<<<256, 512, 0, stream>>>(h_b, wqkv_b, q_b, k_b, vT_b, kc, vc);

  k_attn<<<dim3(16, 32), 256, 0, stream>>>(q_b, k_b, vT_b, ao_b);

  // x1 = x + attn @ w_proj^T  (grid 32x16 = 512 blocks)
  k_gemm_skinny<<<512, 256, 0, stream>>>(ao_b, wproj_b, 4096, 1024, 1024, 16,
                                         x, x1);

  k_rms<<<4096, 256, 0, stream>>>(x1, wn2, h_b);

  // act = silu(h2 @ w_gate^T) * (h2 @ w_up^T)  — 2-phase, grid 512, XCD-tiled
  k_mlp<<<512, 512, 0, stream>>>(h_b, wgate_b, wup_b, act_b);

  // split-K down: pc_ks = act @ wdown^T (K halves), then out = x1 + pc0 + pc1
  k_down<<<256, 512, 0, stream>>>(act_b, wdown_b, pc0, pc1);
  k_fin<<<4096, 256, 0, stream>>>(out, pc0, pc1);
}